// Round 1
// baseline (366.702 us; speedup 1.0000x reference)
//
#include <hip/hip_runtime.h>
#include <math.h>

#define N 4096
#define NFEAT 512
#define NHID 64
#define NCLASS 16
#define NHEADS 8
#define ALPHA 0.2f

// ---------------------------------------------------------------------------
// K1: h[hd][i][d] = x[i][:] @ Wh[hd][:][d]   (M=4096, K=512, Nc=64 per head)
// 64x64 tile per block, 256 threads, 4x4 micro-tile, K staged in 32-chunks.
// ---------------------------------------------------------------------------
__global__ __launch_bounds__(256) void k_gemm_h(const float* __restrict__ x,
                                                const float* __restrict__ Wh,
                                                float* __restrict__ h) {
  const int tile = blockIdx.x, hd = blockIdx.y;
  const int i0 = tile * 64;
  const float* __restrict__ W = Wh + (size_t)hd * (NFEAT * NHID);
  __shared__ float xs[64][36];  // stride 36 (16B-aligned rows)
  __shared__ float ws[32][68];  // stride 68 (16B-aligned rows)
  const int t = threadIdx.x;
  const int ti = t >> 4, tj = t & 15;
  float acc[4][4] = {{0.f, 0.f, 0.f, 0.f}, {0.f, 0.f, 0.f, 0.f},
                     {0.f, 0.f, 0.f, 0.f}, {0.f, 0.f, 0.f, 0.f}};
  for (int k0 = 0; k0 < NFEAT; k0 += 32) {
#pragma unroll
    for (int rep = 0; rep < 2; ++rep) {
      int f4 = t + rep * 256;
      int r = f4 >> 3, c4 = f4 & 7;  // x tile: 64 rows x 8 float4
      float4 v = *(const float4*)(x + (size_t)(i0 + r) * NFEAT + k0 + c4 * 4);
      xs[r][c4 * 4 + 0] = v.x; xs[r][c4 * 4 + 1] = v.y;
      xs[r][c4 * 4 + 2] = v.z; xs[r][c4 * 4 + 3] = v.w;
      int r2 = f4 >> 4, c42 = f4 & 15;  // W tile: 32 rows x 16 float4
      float4 w = *(const float4*)(W + (size_t)(k0 + r2) * NHID + c42 * 4);
      ws[r2][c42 * 4 + 0] = w.x; ws[r2][c42 * 4 + 1] = w.y;
      ws[r2][c42 * 4 + 2] = w.z; ws[r2][c42 * 4 + 3] = w.w;
    }
    __syncthreads();
#pragma unroll
    for (int kk = 0; kk < 32; ++kk) {
      float4 bv = *(const float4*)&ws[kk][tj * 4];
      float a0 = xs[ti * 4 + 0][kk], a1 = xs[ti * 4 + 1][kk];
      float a2 = xs[ti * 4 + 2][kk], a3 = xs[ti * 4 + 3][kk];
      acc[0][0] += a0 * bv.x; acc[0][1] += a0 * bv.y; acc[0][2] += a0 * bv.z; acc[0][3] += a0 * bv.w;
      acc[1][0] += a1 * bv.x; acc[1][1] += a1 * bv.y; acc[1][2] += a1 * bv.z; acc[1][3] += a1 * bv.w;
      acc[2][0] += a2 * bv.x; acc[2][1] += a2 * bv.y; acc[2][2] += a2 * bv.z; acc[2][3] += a2 * bv.w;
      acc[3][0] += a3 * bv.x; acc[3][1] += a3 * bv.y; acc[3][2] += a3 * bv.z; acc[3][3] += a3 * bv.w;
    }
    __syncthreads();
  }
#pragma unroll
  for (int u = 0; u < 4; ++u) {
    float4 o = make_float4(acc[u][0], acc[u][1], acc[u][2], acc[u][3]);
    *(float4*)(h + ((size_t)hd * N + i0 + ti * 4 + u) * NHID + tj * 4) = o;
  }
}

// ---------------------------------------------------------------------------
// K2: s_src[hd][i] = h_row . a[:F], s_dst = h_row . a[F:]. One wave per row.
// ---------------------------------------------------------------------------
__global__ __launch_bounds__(256) void k_scores(const float* __restrict__ h,
                                                const float* __restrict__ a,
                                                float* __restrict__ s_src,
                                                float* __restrict__ s_dst,
                                                int F) {
  int wid = (blockIdx.x * blockDim.x + threadIdx.x) >> 6;
  int lane = threadIdx.x & 63;
  int hd = wid / N;
  const float* hr = h + (size_t)wid * F;
  const float* av = a + (size_t)hd * 2 * F;
  float vs = 0.f, vd = 0.f;
  if (lane < F) {
    float hv = hr[lane];
    vs = hv * av[lane];
    vd = hv * av[F + lane];
  }
#pragma unroll
  for (int m = 32; m; m >>= 1) {
    vs += __shfl_xor(vs, m);
    vd += __shfl_xor(vd, m);
  }
  if (lane == 0) { s_src[wid] = vs; s_dst[wid] = vd; }
}

// ---------------------------------------------------------------------------
// K3: per-head max of t = s_dst
// ---------------------------------------------------------------------------
__global__ __launch_bounds__(256) void k_maxred(const float* __restrict__ t,
                                                float* __restrict__ tmax) {
  int hd = blockIdx.x;
  const float* p = t + (size_t)hd * N;
  float m = -1e30f;
  for (int i = threadIdx.x; i < N; i += 256) m = fmaxf(m, p[i]);
  __shared__ float sm[256];
  sm[threadIdx.x] = m;
  __syncthreads();
  for (int s = 128; s; s >>= 1) {
    if (threadIdx.x < (unsigned)s) sm[threadIdx.x] = fmaxf(sm[threadIdx.x], sm[threadIdx.x + s]);
    __syncthreads();
  }
  if (threadIdx.x == 0) tmax[hd] = sm[0];
}

// ---------------------------------------------------------------------------
// K4: per-head bitonic sort of t (ascending) with permutation, in LDS.
// ---------------------------------------------------------------------------
__global__ __launch_bounds__(1024) void k_sort(const float* __restrict__ t,
                                               float* __restrict__ ts,
                                               int* __restrict__ perm) {
  int hd = blockIdx.x;
  __shared__ float v[N];
  __shared__ int ix[N];
  for (int i = threadIdx.x; i < N; i += 1024) { v[i] = t[(size_t)hd * N + i]; ix[i] = i; }
  __syncthreads();
  for (int k = 2; k <= N; k <<= 1) {
    for (int j = k >> 1; j; j >>= 1) {
      for (int i = threadIdx.x; i < N; i += 1024) {
        int l = i ^ j;
        if (l > i) {
          bool up = ((i & k) == 0);
          float vi = v[i], vl = v[l];
          bool sw = up ? (vi > vl) : (vi < vl);
          if (sw) {
            v[i] = vl; v[l] = vi;
            int tmp = ix[i]; ix[i] = ix[l]; ix[l] = tmp;
          }
        }
      }
      __syncthreads();
    }
  }
  for (int i = threadIdx.x; i < N; i += 1024) {
    ts[(size_t)hd * N + i] = v[i];
    perm[(size_t)hd * N + i] = ix[i];
  }
}

// ---------------------------------------------------------------------------
// K5a: per-chunk sums of eA*g and eB*g (64 rows per chunk).
//   eA_r = exp(ALPHA*(t_r - tmax)), eB_r = exp(t_r - tmax), g = [h_row, 1]
// ---------------------------------------------------------------------------
__global__ __launch_bounds__(64) void k_chunksum(const float* __restrict__ ts,
                                                 const int* __restrict__ perm,
                                                 const float* __restrict__ h,
                                                 const float* __restrict__ tmax,
                                                 float* __restrict__ csA,
                                                 float* __restrict__ csB,
                                                 float* __restrict__ csAz,
                                                 float* __restrict__ csBz,
                                                 int F) {
  int chunk = blockIdx.x, hd = blockIdx.y, lane = threadIdx.x;
  int r0 = chunk * 64;
  float tm = tmax[hd];
  float sA = 0.f, sB = 0.f, sAz = 0.f, sBz = 0.f;
  for (int r = 0; r < 64; ++r) {
    float tv = ts[(size_t)hd * N + r0 + r];
    int p = perm[(size_t)hd * N + r0 + r];
    float eA = expf(ALPHA * (tv - tm));
    float eB = expf(tv - tm);
    float hv = (lane < F) ? h[((size_t)hd * N + p) * F + lane] : 0.f;
    sA += eA * hv; sB += eB * hv;
    sAz += eA; sBz += eB;
  }
  if (lane < F) {
    csA[((size_t)hd * 64 + chunk) * F + lane] = sA;
    csB[((size_t)hd * 64 + chunk) * F + lane] = sB;
  }
  if (lane == 0) { csAz[hd * 64 + chunk] = sAz; csBz[hd * 64 + chunk] = sBz; }
}

// ---------------------------------------------------------------------------
// K5b: in-place exclusive scan of chunk sums. A: ascending prefix; B:
// descending suffix (sum of chunks strictly AFTER c).
// ---------------------------------------------------------------------------
__global__ __launch_bounds__(64) void k_chunkscan(float* __restrict__ csA,
                                                  float* __restrict__ csB,
                                                  float* __restrict__ csAz,
                                                  float* __restrict__ csBz,
                                                  int F) {
  int hd = blockIdx.x, lane = threadIdx.x;
  if (lane < F) {
    float run = 0.f;
    for (int c = 0; c < 64; ++c) {
      size_t off = ((size_t)hd * 64 + c) * F + lane;
      float tmp = csA[off]; csA[off] = run; run += tmp;
    }
    float runb = 0.f;
    for (int c = 63; c >= 0; --c) {
      size_t off = ((size_t)hd * 64 + c) * F + lane;
      float tmp = csB[off]; csB[off] = runb; runb += tmp;
    }
  }
  if (lane == 0) {
    float run = 0.f;
    for (int c = 0; c < 64; ++c) { float tmp = csAz[hd * 64 + c]; csAz[hd * 64 + c] = run; run += tmp; }
    float runb = 0.f;
    for (int c = 63; c >= 0; --c) { float tmp = csBz[hd * 64 + c]; csBz[hd * 64 + c] = runb; runb += tmp; }
  }
}

// ---------------------------------------------------------------------------
// K5c: fill full prefix P[k]=sum_{r<k} eA*g (ascending, exclusive) and
// suffix Q[k]=sum_{r>=k} eB*g (stored directly, no cancellation).
// P[N]=total_A, Q[N]=0 written by chunk 63.
// ---------------------------------------------------------------------------
__global__ __launch_bounds__(64) void k_prefix(const float* __restrict__ ts,
                                               const int* __restrict__ perm,
                                               const float* __restrict__ h,
                                               const float* __restrict__ tmax,
                                               const float* __restrict__ csA,
                                               const float* __restrict__ csB,
                                               const float* __restrict__ csAz,
                                               const float* __restrict__ csBz,
                                               float* __restrict__ P,
                                               float* __restrict__ Q,
                                               float* __restrict__ Pz,
                                               float* __restrict__ Qz,
                                               int F) {
  int chunk = blockIdx.x, hd = blockIdx.y, lane = threadIdx.x;
  int r0 = chunk * 64;
  float tm = tmax[hd];
  size_t base = (size_t)hd * (N + 1);
  float accA = (lane < F) ? csA[((size_t)hd * 64 + chunk) * F + lane] : 0.f;
  float accAz = csAz[hd * 64 + chunk];
  for (int r = 0; r < 64; ++r) {
    float tv = ts[(size_t)hd * N + r0 + r];
    int p = perm[(size_t)hd * N + r0 + r];
    float eA = expf(ALPHA * (tv - tm));
    float hv = (lane < F) ? h[((size_t)hd * N + p) * F + lane] : 0.f;
    if (lane < F) P[(base + r0 + r) * F + lane] = accA;
    if (lane == 0) Pz[base + r0 + r] = accAz;
    accA += eA * hv;
    accAz += eA;
  }
  if (chunk == 63) {
    if (lane < F) P[(base + N) * F + lane] = accA;
    if (lane == 0) Pz[base + N] = accAz;
    if (lane < F) Q[(base + N) * F + lane] = 0.f;
    if (lane == 0) Qz[base + N] = 0.f;
  }
  float accB = (lane < F) ? csB[((size_t)hd * 64 + chunk) * F + lane] : 0.f;
  float accBz = csBz[hd * 64 + chunk];
  for (int r = 63; r >= 0; --r) {
    float tv = ts[(size_t)hd * N + r0 + r];
    int p = perm[(size_t)hd * N + r0 + r];
    float eB = expf(tv - tm);
    float hv = (lane < F) ? h[((size_t)hd * N + p) * F + lane] : 0.f;
    accB += eB * hv;
    accBz += eB;
    if (lane < F) Q[(base + r0 + r) * F + lane] = accB;
    if (lane == 0) Qz[base + r0 + r] = accBz;
  }
}

// ---------------------------------------------------------------------------
// K6: layer-1 combine: binary search split, blend branches, ELU, write xc
// (head-major concat). One wave per (head,row), lane = hidden dim.
// ---------------------------------------------------------------------------
__global__ __launch_bounds__(256) void k_combine1(const float* __restrict__ s_src,
                                                  const float* __restrict__ ts,
                                                  const float* __restrict__ tmax,
                                                  const float* __restrict__ P,
                                                  const float* __restrict__ Q,
                                                  const float* __restrict__ Pz,
                                                  const float* __restrict__ Qz,
                                                  float* __restrict__ xc) {
  int wid = (blockIdx.x * 256 + threadIdx.x) >> 6;
  int lane = threadIdx.x & 63;
  int hd = wid / N, i = wid % N;
  float s = s_src[wid];
  float key = -s;
  const float* tsh = ts + (size_t)hd * N;
  int lo = 0, hi = N;
  while (lo < hi) {
    int mid = (lo + hi) >> 1;
    if (tsh[mid] <= key) lo = mid + 1; else hi = mid;
  }
  int k = lo;  // first index with t > -s  (negative branch = [0,k))
  float tm = tmax[hd];
  float v = s + tm;
  float m = fmaxf(v, ALPHA * v);           // = LeakyReLU(v) = row max of scores
  float wA = expf(ALPHA * v - m);
  float wB = expf(v - m);
  size_t idx = (size_t)hd * (N + 1) + k;
  float Z = wA * Pz[idx] + wB * Qz[idx];
  float num = wA * P[idx * NHID + lane] + wB * Q[idx * NHID + lane];
  float f = num / Z;
  float e = f > 0.f ? f : expf(f) - 1.f;   // ELU
  xc[(size_t)i * (NHEADS * NHID) + hd * NHID + lane] = e;
}

// ---------------------------------------------------------------------------
// K7: h2 = xc @ Wo  (4096x512 @ 512x16)
// ---------------------------------------------------------------------------
__global__ __launch_bounds__(256) void k_gemm2(const float* __restrict__ xc,
                                               const float* __restrict__ Wo,
                                               float* __restrict__ h2) {
  int row = blockIdx.x * 16 + (threadIdx.x >> 4);
  int col = threadIdx.x & 15;
  const float* xr = xc + (size_t)row * (NHEADS * NHID);
  float acc = 0.f;
  for (int k = 0; k < NHEADS * NHID; k += 4) {
    acc += xr[k + 0] * Wo[(k + 0) * NCLASS + col];
    acc += xr[k + 1] * Wo[(k + 1) * NCLASS + col];
    acc += xr[k + 2] * Wo[(k + 2) * NCLASS + col];
    acc += xr[k + 3] * Wo[(k + 3) * NCLASS + col];
  }
  h2[(size_t)row * NCLASS + col] = acc;
}

// ---------------------------------------------------------------------------
// K8: layer-2 combine + ELU + log_softmax. 16 lanes per row.
// ---------------------------------------------------------------------------
__global__ __launch_bounds__(256) void k_combine2(const float* __restrict__ s_src,
                                                  const float* __restrict__ ts,
                                                  const float* __restrict__ tmax,
                                                  const float* __restrict__ P,
                                                  const float* __restrict__ Q,
                                                  const float* __restrict__ Pz,
                                                  const float* __restrict__ Qz,
                                                  float* __restrict__ out) {
  int i = blockIdx.x * 16 + (threadIdx.x >> 4);
  int c = threadIdx.x & 15;
  float s = s_src[i];
  float key = -s;
  int lo = 0, hi = N;
  while (lo < hi) {
    int mid = (lo + hi) >> 1;
    if (ts[mid] <= key) lo = mid + 1; else hi = mid;
  }
  int k = lo;
  float tm = tmax[0];
  float v = s + tm;
  float m = fmaxf(v, ALPHA * v);
  float wA = expf(ALPHA * v - m);
  float wB = expf(v - m);
  float Z = wA * Pz[k] + wB * Qz[k];
  float num = wA * P[(size_t)k * NCLASS + c] + wB * Q[(size_t)k * NCLASS + c];
  float f = num / Z;
  float o = f > 0.f ? f : expf(f) - 1.f;  // ELU
  // log_softmax over the 16 classes (contiguous 16-lane group)
  float mx = o;
#pragma unroll
  for (int mk = 1; mk < 16; mk <<= 1) mx = fmaxf(mx, __shfl_xor(mx, mk, 16));
  float ex = expf(o - mx);
  float sum = ex;
#pragma unroll
  for (int mk = 1; mk < 16; mk <<= 1) sum += __shfl_xor(sum, mk, 16);
  out[(size_t)i * NCLASS + c] = o - mx - logf(sum);
}

// ---------------------------------------------------------------------------
extern "C" void kernel_launch(void* const* d_in, const int* in_sizes, int n_in,
                              void* d_out, int out_size, void* d_ws, size_t ws_size,
                              hipStream_t stream) {
  const float* x  = (const float*)d_in[0];
  const float* Wh = (const float*)d_in[1];
  const float* ah = (const float*)d_in[2];
  const float* Wo = (const float*)d_in[3];
  const float* ao = (const float*)d_in[4];
  float* out = (float*)d_out;

  char* base = (char*)d_ws;
  size_t off = 0;
  auto alloc_f = [&](size_t n) -> float* {
    float* p = (float*)(base + off);
    off = (off + n * sizeof(float) + 255) & ~(size_t)255;
    return p;
  };
  auto alloc_i = [&](size_t n) -> int* {
    int* p = (int*)(base + off);
    off = (off + n * sizeof(int) + 255) & ~(size_t)255;
    return p;
  };

  float* h1    = alloc_f((size_t)NHEADS * N * NHID);
  float* ssrc1 = alloc_f((size_t)NHEADS * N);
  float* sdst1 = alloc_f((size_t)NHEADS * N);
  float* tmax1 = alloc_f(NHEADS);
  float* ts1   = alloc_f((size_t)NHEADS * N);
  int*   perm1 = alloc_i((size_t)NHEADS * N);
  float* csA1  = alloc_f((size_t)NHEADS * 64 * NHID);
  float* csB1  = alloc_f((size_t)NHEADS * 64 * NHID);
  float* csAz1 = alloc_f(NHEADS * 64);
  float* csBz1 = alloc_f(NHEADS * 64);
  float* P1    = alloc_f((size_t)NHEADS * (N + 1) * NHID);
  float* Q1    = alloc_f((size_t)NHEADS * (N + 1) * NHID);
  float* Pz1   = alloc_f((size_t)NHEADS * (N + 1));
  float* Qz1   = alloc_f((size_t)NHEADS * (N + 1));
  float* xc    = alloc_f((size_t)N * NHEADS * NHID);
  float* h2    = alloc_f((size_t)N * NCLASS);
  float* ssrc2 = alloc_f(N);
  float* sdst2 = alloc_f(N);
  float* tmax2 = alloc_f(8);
  float* ts2   = alloc_f(N);
  int*   perm2 = alloc_i(N);
  float* csA2  = alloc_f(64 * NCLASS);
  float* csB2  = alloc_f(64 * NCLASS);
  float* csAz2 = alloc_f(64);
  float* csBz2 = alloc_f(64);
  float* P2    = alloc_f((size_t)(N + 1) * NCLASS);
  float* Q2    = alloc_f((size_t)(N + 1) * NCLASS);
  float* Pz2   = alloc_f(N + 1);
  float* Qz2   = alloc_f(N + 1);

  if (off > ws_size) return;  // workspace too small -> output stays poisoned

  // ---- Layer 1 (8 heads) ----
  hipLaunchKernelGGL(k_gemm_h, dim3(64, NHEADS), dim3(256), 0, stream, x, Wh, h1);
  hipLaunchKernelGGL(k_scores, dim3(NHEADS * N / 4), dim3(256), 0, stream, h1, ah, ssrc1, sdst1, NHID);
  hipLaunchKernelGGL(k_maxred, dim3(NHEADS), dim3(256), 0, stream, sdst1, tmax1);
  hipLaunchKernelGGL(k_sort, dim3(NHEADS), dim3(1024), 0, stream, sdst1, ts1, perm1);
  hipLaunchKernelGGL(k_chunksum, dim3(64, NHEADS), dim3(64), 0, stream, ts1, perm1, h1, tmax1, csA1, csB1, csAz1, csBz1, NHID);
  hipLaunchKernelGGL(k_chunkscan, dim3(NHEADS), dim3(64), 0, stream, csA1, csB1, csAz1, csBz1, NHID);
  hipLaunchKernelGGL(k_prefix, dim3(64, NHEADS), dim3(64), 0, stream, ts1, perm1, h1, tmax1, csA1, csB1, csAz1, csBz1, P1, Q1, Pz1, Qz1, NHID);
  hipLaunchKernelGGL(k_combine1, dim3(NHEADS * N / 4), dim3(256), 0, stream, ssrc1, ts1, tmax1, P1, Q1, Pz1, Qz1, xc);

  // ---- Layer 2 (1 "head", F=16) ----
  hipLaunchKernelGGL(k_gemm2, dim3(N / 16), dim3(256), 0, stream, xc, Wo, h2);
  hipLaunchKernelGGL(k_scores, dim3(N / 4), dim3(256), 0, stream, h2, ao, ssrc2, sdst2, NCLASS);
  hipLaunchKernelGGL(k_maxred, dim3(1), dim3(256), 0, stream, sdst2, tmax2);
  hipLaunchKernelGGL(k_sort, dim3(1), dim3(1024), 0, stream, sdst2, ts2, perm2);
  hipLaunchKernelGGL(k_chunksum, dim3(64, 1), dim3(64), 0, stream, ts2, perm2, h2, tmax2, csA2, csB2, csAz2, csBz2, NCLASS);
  hipLaunchKernelGGL(k_chunkscan, dim3(1), dim3(64), 0, stream, csA2, csB2, csAz2, csBz2, NCLASS);
  hipLaunchKernelGGL(k_prefix, dim3(64, 1), dim3(64), 0, stream, ts2, perm2, h2, tmax2, csA2, csB2, csAz2, csBz2, P2, Q2, Pz2, Qz2, NCLASS);
  hipLaunchKernelGGL(k_combine2, dim3(N / 16), dim3(256), 0, stream, ssrc2, ts2, tmax2, P2, Q2, Pz2, Qz2, out);
}

// Round 2
// 230.961 us; speedup vs baseline: 1.5877x; 1.5877x over previous
//
#include <hip/hip_runtime.h>
#include <math.h>

#define N 4096
#define NFEAT 512
#define NHID 64
#define NCLASS 16
#define NHEADS 8
#define ALPHA 0.2f

// ---------------------------------------------------------------------------
// K1: h[hd][i][d] = x[i][:] @ Wh[hd][:][d]   (M=4096, K=512, Nc=64 per head)
// 64x64 tile per block, 256 threads, 4x4 micro-tile, K staged in 32-chunks.
// ---------------------------------------------------------------------------
__global__ __launch_bounds__(256) void k_gemm_h(const float* __restrict__ x,
                                                const float* __restrict__ Wh,
                                                float* __restrict__ h) {
  const int tile = blockIdx.x, hd = blockIdx.y;
  const int i0 = tile * 64;
  const float* __restrict__ W = Wh + (size_t)hd * (NFEAT * NHID);
  __shared__ float xs[64][36];  // stride 36 (16B-aligned rows)
  __shared__ float ws[32][68];  // stride 68 (16B-aligned rows)
  const int t = threadIdx.x;
  const int ti = t >> 4, tj = t & 15;
  float acc[4][4] = {{0.f, 0.f, 0.f, 0.f}, {0.f, 0.f, 0.f, 0.f},
                     {0.f, 0.f, 0.f, 0.f}, {0.f, 0.f, 0.f, 0.f}};
  for (int k0 = 0; k0 < NFEAT; k0 += 32) {
#pragma unroll
    for (int rep = 0; rep < 2; ++rep) {
      int f4 = t + rep * 256;
      int r = f4 >> 3, c4 = f4 & 7;  // x tile: 64 rows x 8 float4
      float4 v = *(const float4*)(x + (size_t)(i0 + r) * NFEAT + k0 + c4 * 4);
      xs[r][c4 * 4 + 0] = v.x; xs[r][c4 * 4 + 1] = v.y;
      xs[r][c4 * 4 + 2] = v.z; xs[r][c4 * 4 + 3] = v.w;
      int r2 = f4 >> 4, c42 = f4 & 15;  // W tile: 32 rows x 16 float4
      float4 w = *(const float4*)(W + (size_t)(k0 + r2) * NHID + c42 * 4);
      ws[r2][c42 * 4 + 0] = w.x; ws[r2][c42 * 4 + 1] = w.y;
      ws[r2][c42 * 4 + 2] = w.z; ws[r2][c42 * 4 + 3] = w.w;
    }
    __syncthreads();
#pragma unroll
    for (int kk = 0; kk < 32; ++kk) {
      float4 bv = *(const float4*)&ws[kk][tj * 4];
      float a0 = xs[ti * 4 + 0][kk], a1 = xs[ti * 4 + 1][kk];
      float a2 = xs[ti * 4 + 2][kk], a3 = xs[ti * 4 + 3][kk];
      acc[0][0] += a0 * bv.x; acc[0][1] += a0 * bv.y; acc[0][2] += a0 * bv.z; acc[0][3] += a0 * bv.w;
      acc[1][0] += a1 * bv.x; acc[1][1] += a1 * bv.y; acc[1][2] += a1 * bv.z; acc[1][3] += a1 * bv.w;
      acc[2][0] += a2 * bv.x; acc[2][1] += a2 * bv.y; acc[2][2] += a2 * bv.z; acc[2][3] += a2 * bv.w;
      acc[3][0] += a3 * bv.x; acc[3][1] += a3 * bv.y; acc[3][2] += a3 * bv.z; acc[3][3] += a3 * bv.w;
    }
    __syncthreads();
  }
#pragma unroll
  for (int u = 0; u < 4; ++u) {
    float4 o = make_float4(acc[u][0], acc[u][1], acc[u][2], acc[u][3]);
    *(float4*)(h + ((size_t)hd * N + i0 + ti * 4 + u) * NHID + tj * 4) = o;
  }
}

// ---------------------------------------------------------------------------
// K2: s_src[hd][i] = h_row . a[:F], s_dst = h_row . a[F:]. One wave per row.
// ---------------------------------------------------------------------------
__global__ __launch_bounds__(256) void k_scores(const float* __restrict__ h,
                                                const float* __restrict__ a,
                                                float* __restrict__ s_src,
                                                float* __restrict__ s_dst,
                                                int F) {
  int wid = (blockIdx.x * blockDim.x + threadIdx.x) >> 6;
  int lane = threadIdx.x & 63;
  int hd = wid / N;
  const float* hr = h + (size_t)wid * F;
  const float* av = a + (size_t)hd * 2 * F;
  float vs = 0.f, vd = 0.f;
  if (lane < F) {
    float hv = hr[lane];
    vs = hv * av[lane];
    vd = hv * av[F + lane];
  }
#pragma unroll
  for (int m = 32; m; m >>= 1) {
    vs += __shfl_xor(vs, m);
    vd += __shfl_xor(vd, m);
  }
  if (lane == 0) { s_src[wid] = vs; s_dst[wid] = vd; }
}

// ---------------------------------------------------------------------------
// K4': counting rank (replaces bitonic sort). Unique 64-bit keys
// (monotone float bits << 12 | index) in LDS; each element's count of
// smaller keys is split across 4 waves and combined via LDS atomics;
// scatter gives ascending-sorted ts + permutation. tmax == ts[N-1].
// ---------------------------------------------------------------------------
__global__ __launch_bounds__(1024) void k_rank(const float* __restrict__ t,
                                               float* __restrict__ ts,
                                               int* __restrict__ perm) {
  int hd = blockIdx.y;
  int tid = threadIdx.x;
  int jloc = tid & 255;
  int j = blockIdx.x * 256 + jloc;
  int q = tid >> 8;  // wave-uniform quarter index 0..3
  __shared__ unsigned long long skey[N];  // 32 KB
  __shared__ int scnt[256];
  const float* th = t + (size_t)hd * N;
  for (int i = tid; i < N; i += 1024) {
    unsigned u = __float_as_uint(th[i]);
    u = (u & 0x80000000u) ? ~u : (u | 0x80000000u);  // monotone total order
    skey[i] = ((unsigned long long)u << 12) | (unsigned)i;  // unique keys
  }
  if (tid < 256) scnt[tid] = 0;
  __syncthreads();
  unsigned long long kj = skey[j];
  int cnt = 0;
  const int l0 = q * 1024;
#pragma unroll 8
  for (int l = 0; l < 1024; ++l) {
    cnt += (skey[l0 + l] < kj) ? 1 : 0;  // wave-uniform LDS broadcast read
  }
  atomicAdd(&scnt[jloc], cnt);
  __syncthreads();
  if (q == 0) {
    int r = scnt[jloc];
    ts[(size_t)hd * N + r] = th[j];
    perm[(size_t)hd * N + r] = j;
  }
}

// ---------------------------------------------------------------------------
// K5a: per-chunk sums of eA*g and eB*g (64 rows per chunk).
//   eA_r = exp(ALPHA*(t_r - tmax)), eB_r = exp(t_r - tmax), g = [h_row, 1]
// ---------------------------------------------------------------------------
__global__ __launch_bounds__(64) void k_chunksum(const float* __restrict__ ts,
                                                 const int* __restrict__ perm,
                                                 const float* __restrict__ h,
                                                 float* __restrict__ csA,
                                                 float* __restrict__ csB,
                                                 float* __restrict__ csAz,
                                                 float* __restrict__ csBz,
                                                 int F) {
  int chunk = blockIdx.x, hd = blockIdx.y, lane = threadIdx.x;
  int r0 = chunk * 64;
  float tm = ts[(size_t)hd * N + N - 1];
  float sA = 0.f, sB = 0.f, sAz = 0.f, sBz = 0.f;
  for (int r = 0; r < 64; ++r) {
    float tv = ts[(size_t)hd * N + r0 + r];
    int p = perm[(size_t)hd * N + r0 + r];
    float eA = expf(ALPHA * (tv - tm));
    float eB = expf(tv - tm);
    float hv = (lane < F) ? h[((size_t)hd * N + p) * F + lane] : 0.f;
    sA += eA * hv; sB += eB * hv;
    sAz += eA; sBz += eB;
  }
  if (lane < F) {
    csA[((size_t)hd * 64 + chunk) * F + lane] = sA;
    csB[((size_t)hd * 64 + chunk) * F + lane] = sB;
  }
  if (lane == 0) { csAz[hd * 64 + chunk] = sAz; csBz[hd * 64 + chunk] = sBz; }
}

// ---------------------------------------------------------------------------
// K5b: in-place exclusive scan of chunk sums. A: ascending prefix; B:
// descending suffix (sum of chunks strictly AFTER c). Register-staged so
// loads pipeline.
// ---------------------------------------------------------------------------
__global__ __launch_bounds__(64) void k_chunkscan(float* __restrict__ csA,
                                                  float* __restrict__ csB,
                                                  float* __restrict__ csAz,
                                                  float* __restrict__ csBz,
                                                  int F) {
  int hd = blockIdx.x, lane = threadIdx.x;
  if (lane < F) {
    float vA[64], vB[64];
#pragma unroll
    for (int c = 0; c < 64; ++c) vA[c] = csA[((size_t)hd * 64 + c) * F + lane];
#pragma unroll
    for (int c = 0; c < 64; ++c) vB[c] = csB[((size_t)hd * 64 + c) * F + lane];
    float run = 0.f;
#pragma unroll
    for (int c = 0; c < 64; ++c) { float tmp = vA[c]; vA[c] = run; run += tmp; }
    float runb = 0.f;
#pragma unroll
    for (int c = 63; c >= 0; --c) { float tmp = vB[c]; vB[c] = runb; runb += tmp; }
#pragma unroll
    for (int c = 0; c < 64; ++c) csA[((size_t)hd * 64 + c) * F + lane] = vA[c];
#pragma unroll
    for (int c = 0; c < 64; ++c) csB[((size_t)hd * 64 + c) * F + lane] = vB[c];
  }
  if (lane == 0) {
    float run = 0.f;
    for (int c = 0; c < 64; ++c) { float tmp = csAz[hd * 64 + c]; csAz[hd * 64 + c] = run; run += tmp; }
    float runb = 0.f;
    for (int c = 63; c >= 0; --c) { float tmp = csBz[hd * 64 + c]; csBz[hd * 64 + c] = runb; runb += tmp; }
  }
}

// ---------------------------------------------------------------------------
// K5c: fill full prefix P[k]=sum_{r<k} eA*g (ascending, exclusive) and
// suffix Q[k]=sum_{r>=k} eB*g (stored directly, no cancellation).
// P[N]=total_A, Q[N]=0 written by chunk 63.
// ---------------------------------------------------------------------------
__global__ __launch_bounds__(64) void k_prefix(const float* __restrict__ ts,
                                               const int* __restrict__ perm,
                                               const float* __restrict__ h,
                                               const float* __restrict__ csA,
                                               const float* __restrict__ csB,
                                               const float* __restrict__ csAz,
                                               const float* __restrict__ csBz,
                                               float* __restrict__ P,
                                               float* __restrict__ Q,
                                               float* __restrict__ Pz,
                                               float* __restrict__ Qz,
                                               int F) {
  int chunk = blockIdx.x, hd = blockIdx.y, lane = threadIdx.x;
  int r0 = chunk * 64;
  float tm = ts[(size_t)hd * N + N - 1];
  size_t base = (size_t)hd * (N + 1);
  float accA = (lane < F) ? csA[((size_t)hd * 64 + chunk) * F + lane] : 0.f;
  float accAz = csAz[hd * 64 + chunk];
  for (int r = 0; r < 64; ++r) {
    float tv = ts[(size_t)hd * N + r0 + r];
    int p = perm[(size_t)hd * N + r0 + r];
    float eA = expf(ALPHA * (tv - tm));
    float hv = (lane < F) ? h[((size_t)hd * N + p) * F + lane] : 0.f;
    if (lane < F) P[(base + r0 + r) * F + lane] = accA;
    if (lane == 0) Pz[base + r0 + r] = accAz;
    accA += eA * hv;
    accAz += eA;
  }
  if (chunk == 63) {
    if (lane < F) P[(base + N) * F + lane] = accA;
    if (lane == 0) Pz[base + N] = accAz;
    if (lane < F) Q[(base + N) * F + lane] = 0.f;
    if (lane == 0) Qz[base + N] = 0.f;
  }
  float accB = (lane < F) ? csB[((size_t)hd * 64 + chunk) * F + lane] : 0.f;
  float accBz = csBz[hd * 64 + chunk];
  for (int r = 63; r >= 0; --r) {
    float tv = ts[(size_t)hd * N + r0 + r];
    int p = perm[(size_t)hd * N + r0 + r];
    float eB = expf(tv - tm);
    float hv = (lane < F) ? h[((size_t)hd * N + p) * F + lane] : 0.f;
    accB += eB * hv;
    accBz += eB;
    if (lane < F) Q[(base + r0 + r) * F + lane] = accB;
    if (lane == 0) Qz[base + r0 + r] = accBz;
  }
}

// ---------------------------------------------------------------------------
// K6: layer-1 combine: binary search split, blend branches, ELU, write xc
// (head-major concat). One wave per (head,row), lane = hidden dim.
// ---------------------------------------------------------------------------
__global__ __launch_bounds__(256) void k_combine1(const float* __restrict__ s_src,
                                                  const float* __restrict__ ts,
                                                  const float* __restrict__ P,
                                                  const float* __restrict__ Q,
                                                  const float* __restrict__ Pz,
                                                  const float* __restrict__ Qz,
                                                  float* __restrict__ xc) {
  int wid = (blockIdx.x * 256 + threadIdx.x) >> 6;
  int lane = threadIdx.x & 63;
  int hd = wid / N, i = wid % N;
  float s = s_src[wid];
  float key = -s;
  const float* tsh = ts + (size_t)hd * N;
  int lo = 0, hi = N;
  while (lo < hi) {
    int mid = (lo + hi) >> 1;
    if (tsh[mid] <= key) lo = mid + 1; else hi = mid;
  }
  int k = lo;  // first index with t > -s  (negative branch = [0,k))
  float tm = tsh[N - 1];
  float v = s + tm;
  float m = fmaxf(v, ALPHA * v);           // = LeakyReLU(v) = row max of scores
  float wA = expf(ALPHA * v - m);
  float wB = expf(v - m);
  size_t idx = (size_t)hd * (N + 1) + k;
  float Z = wA * Pz[idx] + wB * Qz[idx];
  float num = wA * P[idx * NHID + lane] + wB * Q[idx * NHID + lane];
  float f = num / Z;
  float e = f > 0.f ? f : expf(f) - 1.f;   // ELU
  xc[(size_t)i * (NHEADS * NHID) + hd * NHID + lane] = e;
}

// ---------------------------------------------------------------------------
// K7: h2 = xc @ Wo  (4096x512 @ 512x16)
// ---------------------------------------------------------------------------
__global__ __launch_bounds__(256) void k_gemm2(const float* __restrict__ xc,
                                               const float* __restrict__ Wo,
                                               float* __restrict__ h2) {
  int row = blockIdx.x * 16 + (threadIdx.x >> 4);
  int col = threadIdx.x & 15;
  const float* xr = xc + (size_t)row * (NHEADS * NHID);
  float acc = 0.f;
  for (int k = 0; k < NHEADS * NHID; k += 4) {
    acc += xr[k + 0] * Wo[(k + 0) * NCLASS + col];
    acc += xr[k + 1] * Wo[(k + 1) * NCLASS + col];
    acc += xr[k + 2] * Wo[(k + 2) * NCLASS + col];
    acc += xr[k + 3] * Wo[(k + 3) * NCLASS + col];
  }
  h2[(size_t)row * NCLASS + col] = acc;
}

// ---------------------------------------------------------------------------
// K8: layer-2 combine + ELU + log_softmax. 16 lanes per row.
// ---------------------------------------------------------------------------
__global__ __launch_bounds__(256) void k_combine2(const float* __restrict__ s_src,
                                                  const float* __restrict__ ts,
                                                  const float* __restrict__ P,
                                                  const float* __restrict__ Q,
                                                  const float* __restrict__ Pz,
                                                  const float* __restrict__ Qz,
                                                  float* __restrict__ out) {
  int i = blockIdx.x * 16 + (threadIdx.x >> 4);
  int c = threadIdx.x & 15;
  float s = s_src[i];
  float key = -s;
  int lo = 0, hi = N;
  while (lo < hi) {
    int mid = (lo + hi) >> 1;
    if (ts[mid] <= key) lo = mid + 1; else hi = mid;
  }
  int k = lo;
  float tm = ts[N - 1];
  float v = s + tm;
  float m = fmaxf(v, ALPHA * v);
  float wA = expf(ALPHA * v - m);
  float wB = expf(v - m);
  float Z = wA * Pz[k] + wB * Qz[k];
  float num = wA * P[(size_t)k * NCLASS + c] + wB * Q[(size_t)k * NCLASS + c];
  float f = num / Z;
  float o = f > 0.f ? f : expf(f) - 1.f;  // ELU
  // log_softmax over the 16 classes (contiguous 16-lane group)
  float mx = o;
#pragma unroll
  for (int mk = 1; mk < 16; mk <<= 1) mx = fmaxf(mx, __shfl_xor(mx, mk, 16));
  float ex = expf(o - mx);
  float sum = ex;
#pragma unroll
  for (int mk = 1; mk < 16; mk <<= 1) sum += __shfl_xor(sum, mk, 16);
  out[(size_t)i * NCLASS + c] = o - mx - logf(sum);
}

// ---------------------------------------------------------------------------
extern "C" void kernel_launch(void* const* d_in, const int* in_sizes, int n_in,
                              void* d_out, int out_size, void* d_ws, size_t ws_size,
                              hipStream_t stream) {
  const float* x  = (const float*)d_in[0];
  const float* Wh = (const float*)d_in[1];
  const float* ah = (const float*)d_in[2];
  const float* Wo = (const float*)d_in[3];
  const float* ao = (const float*)d_in[4];
  float* out = (float*)d_out;

  char* base = (char*)d_ws;
  size_t off = 0;
  auto alloc_f = [&](size_t n) -> float* {
    float* p = (float*)(base + off);
    off = (off + n * sizeof(float) + 255) & ~(size_t)255;
    return p;
  };
  auto alloc_i = [&](size_t n) -> int* {
    int* p = (int*)(base + off);
    off = (off + n * sizeof(int) + 255) & ~(size_t)255;
    return p;
  };

  float* h1    = alloc_f((size_t)NHEADS * N * NHID);
  float* ssrc1 = alloc_f((size_t)NHEADS * N);
  float* sdst1 = alloc_f((size_t)NHEADS * N);
  float* ts1   = alloc_f((size_t)NHEADS * N);
  int*   perm1 = alloc_i((size_t)NHEADS * N);
  float* csA1  = alloc_f((size_t)NHEADS * 64 * NHID);
  float* csB1  = alloc_f((size_t)NHEADS * 64 * NHID);
  float* csAz1 = alloc_f(NHEADS * 64);
  float* csBz1 = alloc_f(NHEADS * 64);
  float* P1    = alloc_f((size_t)NHEADS * (N + 1) * NHID);
  float* Q1    = alloc_f((size_t)NHEADS * (N + 1) * NHID);
  float* Pz1   = alloc_f((size_t)NHEADS * (N + 1));
  float* Qz1   = alloc_f((size_t)NHEADS * (N + 1));
  float* xc    = alloc_f((size_t)N * NHEADS * NHID);
  float* h2    = alloc_f((size_t)N * NCLASS);
  float* ssrc2 = alloc_f(N);
  float* sdst2 = alloc_f(N);
  float* ts2   = alloc_f(N);
  int*   perm2 = alloc_i(N);
  float* csA2  = alloc_f(64 * NCLASS);
  float* csB2  = alloc_f(64 * NCLASS);
  float* csAz2 = alloc_f(64);
  float* csBz2 = alloc_f(64);
  float* P2    = alloc_f((size_t)(N + 1) * NCLASS);
  float* Q2    = alloc_f((size_t)(N + 1) * NCLASS);
  float* Pz2   = alloc_f(N + 1);
  float* Qz2   = alloc_f(N + 1);

  if (off > ws_size) return;  // workspace too small -> output stays poisoned

  // ---- Layer 1 (8 heads) ----
  hipLaunchKernelGGL(k_gemm_h, dim3(64, NHEADS), dim3(256), 0, stream, x, Wh, h1);
  hipLaunchKernelGGL(k_scores, dim3(NHEADS * N / 4), dim3(256), 0, stream, h1, ah, ssrc1, sdst1, NHID);
  hipLaunchKernelGGL(k_rank, dim3(N / 256, NHEADS), dim3(1024), 0, stream, sdst1, ts1, perm1);
  hipLaunchKernelGGL(k_chunksum, dim3(64, NHEADS), dim3(64), 0, stream, ts1, perm1, h1, csA1, csB1, csAz1, csBz1, NHID);
  hipLaunchKernelGGL(k_chunkscan, dim3(NHEADS), dim3(64), 0, stream, csA1, csB1, csAz1, csBz1, NHID);
  hipLaunchKernelGGL(k_prefix, dim3(64, NHEADS), dim3(64), 0, stream, ts1, perm1, h1, csA1, csB1, csAz1, csBz1, P1, Q1, Pz1, Qz1, NHID);
  hipLaunchKernelGGL(k_combine1, dim3(NHEADS * N / 4), dim3(256), 0, stream, ssrc1, ts1, P1, Q1, Pz1, Qz1, xc);

  // ---- Layer 2 (1 "head", F=16) ----
  hipLaunchKernelGGL(k_gemm2, dim3(N / 16), dim3(256), 0, stream, xc, Wo, h2);
  hipLaunchKernelGGL(k_scores, dim3(N / 4), dim3(256), 0, stream, h2, ao, ssrc2, sdst2, NCLASS);
  hipLaunchKernelGGL(k_rank, dim3(N / 256, 1), dim3(1024), 0, stream, sdst2, ts2, perm2);
  hipLaunchKernelGGL(k_chunksum, dim3(64, 1), dim3(64), 0, stream, ts2, perm2, h2, csA2, csB2, csAz2, csBz2, NCLASS);
  hipLaunchKernelGGL(k_chunkscan, dim3(1), dim3(64), 0, stream, csA2, csB2, csAz2, csBz2, NCLASS);
  hipLaunchKernelGGL(k_prefix, dim3(64, 1), dim3(64), 0, stream, ts2, perm2, h2, csA2, csB2, csAz2, csBz2, P2, Q2, Pz2, Qz2, NCLASS);
  hipLaunchKernelGGL(k_combine2, dim3(N / 16), dim3(256), 0, stream, ssrc2, ts2, P2, Q2, Pz2, Qz2, out);
}

// Round 3
// 179.184 us; speedup vs baseline: 2.0465x; 1.2890x over previous
//
#include <hip/hip_runtime.h>
#include <math.h>

#define N 4096
#define NFEAT 512
#define NHID 64
#define NCLASS 16
#define NHEADS 8
#define ALPHA 0.2f
#define NC 256   // chunks per head (16 rows each)

typedef __attribute__((ext_vector_type(8))) short bf16x8;
typedef __attribute__((ext_vector_type(4))) float f32x4;

__device__ inline unsigned short f2bf(float f) {
  unsigned u = __float_as_uint(f);
  unsigned r = u + 0x7fffu + ((u >> 16) & 1u);  // RNE
  return (unsigned short)(r >> 16);
}

// ---------------------------------------------------------------------------
// P0a: pack x (fp32 -> bf16), elementwise.
// ---------------------------------------------------------------------------
__global__ __launch_bounds__(256) void k_pack_x(const float* __restrict__ x,
                                                unsigned short* __restrict__ xb) {
  int i = (blockIdx.x * 256 + threadIdx.x) * 4;
  float4 v = *(const float4*)(x + i);
  ushort4 o;
  o.x = f2bf(v.x); o.y = f2bf(v.y); o.z = f2bf(v.z); o.w = f2bf(v.w);
  *(ushort4*)(xb + i) = o;
}

// ---------------------------------------------------------------------------
// P0b: Wt[hd][n][k] = bf16(Wh[hd][k][n])  (transpose per head via LDS)
// ---------------------------------------------------------------------------
__global__ __launch_bounds__(256) void k_pack_w(const float* __restrict__ Wh,
                                                unsigned short* __restrict__ Wt) {
  int kt = blockIdx.x, hd = blockIdx.y;  // 64-k tile
  __shared__ float ld[64][65];
  const float* src = Wh + ((size_t)hd * NFEAT + kt * 64) * NHID;
  int r = threadIdx.x >> 2, c0 = (threadIdx.x & 3) * 16;
#pragma unroll
  for (int j = 0; j < 4; ++j) {
    float4 v = *(const float4*)(src + (size_t)r * NHID + c0 + j * 4);
    ld[r][c0 + j * 4 + 0] = v.x; ld[r][c0 + j * 4 + 1] = v.y;
    ld[r][c0 + j * 4 + 2] = v.z; ld[r][c0 + j * 4 + 3] = v.w;
  }
  __syncthreads();
  int n = threadIdx.x >> 2, kq = threadIdx.x & 3;
  unsigned short tmp[16];
#pragma unroll
  for (int j = 0; j < 16; ++j) tmp[j] = f2bf(ld[kq * 16 + j][n]);
  unsigned short* dst = Wt + ((size_t)hd * 64 + n) * NFEAT + kt * 64 + kq * 16;
  ((uint4*)dst)[0] = *(uint4*)tmp;
  ((uint4*)dst)[1] = *(uint4*)(tmp + 8);
}

// ---------------------------------------------------------------------------
// K1: MFMA bf16 GEMM h = x @ Wh per head (M=4096,K=512,N=64), 128x64 tile,
// 4 waves (2M x 2N), fused score epilogue (s_src/s_dst).
// ---------------------------------------------------------------------------
__global__ __launch_bounds__(256) void k_gemm_h(const unsigned short* __restrict__ xb,
                                                const unsigned short* __restrict__ Wt,
                                                const float* __restrict__ ah,
                                                float* __restrict__ h,
                                                float* __restrict__ ssrc,
                                                float* __restrict__ sdst) {
  const int hd = blockIdx.y;
  const int i0 = blockIdx.x * 128;
  const int t = threadIdx.x;
  const int w = t >> 6, lane = t & 63;
  const int lr = lane & 15, kg = lane >> 4;
  const int wm = (w & 1) * 64, wn = (w >> 1) * 32;
  __shared__ uint4 Als[128][4];  // 128 rows x 32 bf16, unit-swizzled
  __shared__ uint4 Bls[64][4];
  __shared__ float sredS[128][2];
  __shared__ float sredD[128][2];
  const unsigned short* xrow = xb + (size_t)i0 * NFEAT;
  const unsigned short* wrow = Wt + (size_t)hd * 64 * NFEAT;

  f32x4 acc[4][2];
#pragma unroll
  for (int a = 0; a < 4; ++a)
#pragma unroll
    for (int b = 0; b < 2; ++b) acc[a][b] = (f32x4){0.f, 0.f, 0.f, 0.f};

  const int ra = t >> 1, ua = (t & 1) * 2;   // A staging: row, first unit
  const int rb = t >> 2, ub = t & 3;         // B staging: row(n), unit
  for (int k0 = 0; k0 < NFEAT; k0 += 32) {
    uint4 qa0 = *(const uint4*)(xrow + (size_t)ra * NFEAT + k0 + ua * 8);
    uint4 qa1 = *(const uint4*)(xrow + (size_t)ra * NFEAT + k0 + ua * 8 + 8);
    uint4 qb  = *(const uint4*)(wrow + (size_t)rb * NFEAT + k0 + ub * 8);
    Als[ra][(ua) ^ (ra & 3)] = qa0;
    Als[ra][(ua + 1) ^ (ra & 3)] = qa1;
    Bls[rb][ub ^ (rb & 3)] = qb;
    __syncthreads();
    bf16x8 af[4], bf[2];
#pragma unroll
    for (int mb = 0; mb < 4; ++mb) {
      int row = wm + mb * 16 + lr;
      af[mb] = __builtin_bit_cast(bf16x8, Als[row][kg ^ (row & 3)]);
    }
#pragma unroll
    for (int nb = 0; nb < 2; ++nb) {
      int col = wn + nb * 16 + lr;
      bf[nb] = __builtin_bit_cast(bf16x8, Bls[col][kg ^ (col & 3)]);
    }
#pragma unroll
    for (int mb = 0; mb < 4; ++mb)
#pragma unroll
      for (int nb = 0; nb < 2; ++nb)
        acc[mb][nb] = __builtin_amdgcn_mfma_f32_16x16x32_bf16(af[mb], bf[nb], acc[mb][nb], 0, 0, 0);
    __syncthreads();
  }

  // write h (fp32)
  float* hout = h + ((size_t)hd * N + i0) * NHID;
#pragma unroll
  for (int mb = 0; mb < 4; ++mb)
#pragma unroll
    for (int nb = 0; nb < 2; ++nb) {
      int rbase = wm + mb * 16 + kg * 4;
      int col = wn + nb * 16 + lr;
#pragma unroll
      for (int reg = 0; reg < 4; ++reg)
        hout[(size_t)(rbase + reg) * NHID + col] = acc[mb][nb][reg];
    }

  // fused scores: s_src = h . ah[:64], s_dst = h . ah[64:]
  float aS[2], aD[2];
#pragma unroll
  for (int nb = 0; nb < 2; ++nb) {
    aS[nb] = ah[hd * 128 + wn + nb * 16 + lr];
    aD[nb] = ah[hd * 128 + 64 + wn + nb * 16 + lr];
  }
#pragma unroll
  for (int mb = 0; mb < 4; ++mb)
#pragma unroll
    for (int reg = 0; reg < 4; ++reg) {
      float ps = acc[mb][0][reg] * aS[0] + acc[mb][1][reg] * aS[1];
      float pd = acc[mb][0][reg] * aD[0] + acc[mb][1][reg] * aD[1];
#pragma unroll
      for (int m = 1; m < 16; m <<= 1) { ps += __shfl_xor(ps, m); pd += __shfl_xor(pd, m); }
      if (lr == 0) {
        int rl = wm + mb * 16 + kg * 4 + reg;
        sredS[rl][w >> 1] = ps;
        sredD[rl][w >> 1] = pd;
      }
    }
  __syncthreads();
  if (t < 128) {
    ssrc[(size_t)hd * N + i0 + t] = sredS[t][0] + sredS[t][1];
    sdst[(size_t)hd * N + i0 + t] = sredD[t][0] + sredD[t][1];
  }
}

// ---------------------------------------------------------------------------
// K4: counting rank (ascending sort + permutation). tmax == ts[N-1].
// ---------------------------------------------------------------------------
__global__ __launch_bounds__(1024) void k_rank(const float* __restrict__ t,
                                               float* __restrict__ ts,
                                               int* __restrict__ perm) {
  int hd = blockIdx.y;
  int tid = threadIdx.x;
  int jloc = tid & 255;
  int j = blockIdx.x * 256 + jloc;
  int q = tid >> 8;
  __shared__ unsigned long long skey[N];
  __shared__ int scnt[256];
  const float* th = t + (size_t)hd * N;
  for (int i = tid; i < N; i += 1024) {
    unsigned u = __float_as_uint(th[i]);
    u = (u & 0x80000000u) ? ~u : (u | 0x80000000u);
    skey[i] = ((unsigned long long)u << 12) | (unsigned)i;
  }
  if (tid < 256) scnt[tid] = 0;
  __syncthreads();
  unsigned long long kj = skey[j];
  int cnt = 0;
  const int l0 = q * 1024;
#pragma unroll 8
  for (int l = 0; l < 1024; ++l) cnt += (skey[l0 + l] < kj) ? 1 : 0;
  atomicAdd(&scnt[jloc], cnt);
  __syncthreads();
  if (q == 0) {
    int r = scnt[jloc];
    ts[(size_t)hd * N + r] = th[j];
    perm[(size_t)hd * N + r] = j;
  }
}

// ---------------------------------------------------------------------------
// K5a: per-chunk (16 rows) sums of eA*g and eB*g. One wave per chunk.
// ---------------------------------------------------------------------------
__global__ __launch_bounds__(256) void k_chunksum(const float* __restrict__ ts,
                                                  const int* __restrict__ perm,
                                                  const float* __restrict__ h,
                                                  float* __restrict__ csA,
                                                  float* __restrict__ csB,
                                                  float* __restrict__ csAz,
                                                  float* __restrict__ csBz,
                                                  int F) {
  int hd = blockIdx.y, lane = threadIdx.x & 63;
  int c = blockIdx.x * 4 + (threadIdx.x >> 6);
  int r0 = c * 16;
  float tm = ts[(size_t)hd * N + N - 1];
  float sA = 0.f, sB = 0.f, sAz = 0.f, sBz = 0.f;
  for (int r = 0; r < 16; ++r) {
    float tv = ts[(size_t)hd * N + r0 + r];
    int p = perm[(size_t)hd * N + r0 + r];
    float eA = expf(ALPHA * (tv - tm));
    float eB = expf(tv - tm);
    float hv = (lane < F) ? h[((size_t)hd * N + p) * F + lane] : 0.f;
    sA += eA * hv; sB += eB * hv;
    sAz += eA; sBz += eB;
  }
  if (lane < F) {
    csA[((size_t)hd * NC + c) * F + lane] = sA;
    csB[((size_t)hd * NC + c) * F + lane] = sB;
  }
  if (lane == 0) { csAz[hd * NC + c] = sAz; csBz[hd * NC + c] = sBz; }
}

// ---------------------------------------------------------------------------
// K5b: exclusive scan of 256 chunk sums per head (A ascending, B suffix).
// One 1024-thread block per head; thread=(lane=F-dim, g=16-chunk group).
// ---------------------------------------------------------------------------
__global__ __launch_bounds__(1024) void k_chunkscan(float* __restrict__ csA,
                                                    float* __restrict__ csB,
                                                    float* __restrict__ csAz,
                                                    float* __restrict__ csBz,
                                                    int F) {
  int hd = blockIdx.x;
  int t = threadIdx.x, lane = t & 63, g = t >> 6;
  __shared__ float part[16][64];
  __shared__ float partz[16];
  size_t b0 = ((size_t)hd * NC + g * 16) * F;
  float sA = 0.f, sB = 0.f, sAz = 0.f, sBz = 0.f;
  if (lane < F) {
#pragma unroll 4
    for (int j = 0; j < 16; ++j) sA += csA[b0 + (size_t)j * F + lane];
#pragma unroll 4
    for (int j = 0; j < 16; ++j) sB += csB[b0 + (size_t)j * F + lane];
  }
  if (lane == 0) {
    for (int j = 0; j < 16; ++j) { sAz += csAz[hd * NC + g * 16 + j]; sBz += csBz[hd * NC + g * 16 + j]; }
  }
  if (lane < F) part[g][lane] = sA;
  if (lane == 0) partz[g] = sAz;
  __syncthreads();
  float baseA = 0.f, baseAz = 0.f;
  if (lane < F) for (int g2 = 0; g2 < g; ++g2) baseA += part[g2][lane];
  if (lane == 0) for (int g2 = 0; g2 < g; ++g2) baseAz += partz[g2];
  __syncthreads();
  if (lane < F) part[g][lane] = sB;
  if (lane == 0) partz[g] = sBz;
  __syncthreads();
  float baseB = 0.f, baseBz = 0.f;
  if (lane < F) for (int g2 = g + 1; g2 < 16; ++g2) baseB += part[g2][lane];
  if (lane == 0) for (int g2 = g + 1; g2 < 16; ++g2) baseBz += partz[g2];
  if (lane < F) {
    float run = baseA;
    for (int j = 0; j < 16; ++j) {
      size_t o = b0 + (size_t)j * F + lane;
      float tmp = csA[o]; csA[o] = run; run += tmp;
    }
    run = baseB;
    for (int j = 15; j >= 0; --j) {
      size_t o = b0 + (size_t)j * F + lane;
      float tmp = csB[o]; csB[o] = run; run += tmp;
    }
  }
  if (lane == 0) {
    float run = baseAz;
    for (int j = 0; j < 16; ++j) {
      int o = hd * NC + g * 16 + j;
      float tmp = csAz[o]; csAz[o] = run; run += tmp;
    }
    run = baseBz;
    for (int j = 15; j >= 0; --j) {
      int o = hd * NC + g * 16 + j;
      float tmp = csBz[o]; csBz[o] = run; run += tmp;
    }
  }
}

// ---------------------------------------------------------------------------
// K5c: fill P (exclusive ascending prefix of eA*g) and Q (suffix of eB*g).
// One wave per 16-row chunk.
// ---------------------------------------------------------------------------
__global__ __launch_bounds__(256) void k_prefix(const float* __restrict__ ts,
                                                const int* __restrict__ perm,
                                                const float* __restrict__ h,
                                                const float* __restrict__ csA,
                                                const float* __restrict__ csB,
                                                const float* __restrict__ csAz,
                                                const float* __restrict__ csBz,
                                                float* __restrict__ P,
                                                float* __restrict__ Q,
                                                float* __restrict__ Pz,
                                                float* __restrict__ Qz,
                                                int F) {
  int hd = blockIdx.y, lane = threadIdx.x & 63;
  int c = blockIdx.x * 4 + (threadIdx.x >> 6);
  int r0 = c * 16;
  float tm = ts[(size_t)hd * N + N - 1];
  size_t base = (size_t)hd * (N + 1);
  float accA = (lane < F) ? csA[((size_t)hd * NC + c) * F + lane] : 0.f;
  float accAz = csAz[hd * NC + c];
  for (int r = 0; r < 16; ++r) {
    int row = r0 + r;
    float tv = ts[(size_t)hd * N + row];
    int p = perm[(size_t)hd * N + row];
    float eA = expf(ALPHA * (tv - tm));
    float hv = (lane < F) ? h[((size_t)hd * N + p) * F + lane] : 0.f;
    if (lane < F) P[(base + row) * F + lane] = accA;
    if (lane == 0) Pz[base + row] = accAz;
    accA += eA * hv;
    accAz += eA;
  }
  if (c == NC - 1) {
    if (lane < F) { P[(base + N) * F + lane] = accA; Q[(base + N) * F + lane] = 0.f; }
    if (lane == 0) { Pz[base + N] = accAz; Qz[base + N] = 0.f; }
  }
  float accB = (lane < F) ? csB[((size_t)hd * NC + c) * F + lane] : 0.f;
  float accBz = csBz[hd * NC + c];
  for (int r = 15; r >= 0; --r) {
    int row = r0 + r;
    float tv = ts[(size_t)hd * N + row];
    int p = perm[(size_t)hd * N + row];
    float eB = expf(tv - tm);
    float hv = (lane < F) ? h[((size_t)hd * N + p) * F + lane] : 0.f;
    accB += eB * hv;
    accBz += eB;
    if (lane < F) Q[(base + row) * F + lane] = accB;
    if (lane == 0) Qz[base + row] = accBz;
  }
}

// ---------------------------------------------------------------------------
// K6: layer-1 combine (binary-search split, blend, ELU), head-major concat.
// ---------------------------------------------------------------------------
__global__ __launch_bounds__(256) void k_combine1(const float* __restrict__ s_src,
                                                  const float* __restrict__ ts,
                                                  const float* __restrict__ P,
                                                  const float* __restrict__ Q,
                                                  const float* __restrict__ Pz,
                                                  const float* __restrict__ Qz,
                                                  float* __restrict__ xc) {
  int wid = (blockIdx.x * 256 + threadIdx.x) >> 6;
  int lane = threadIdx.x & 63;
  int hd = wid / N, i = wid % N;
  float s = s_src[wid];
  float key = -s;
  const float* tsh = ts + (size_t)hd * N;
  int lo = 0, hi = N;
  while (lo < hi) {
    int mid = (lo + hi) >> 1;
    if (tsh[mid] <= key) lo = mid + 1; else hi = mid;
  }
  int k = lo;
  float tm = tsh[N - 1];
  float v = s + tm;
  float m = fmaxf(v, ALPHA * v);
  float wA = expf(ALPHA * v - m);
  float wB = expf(v - m);
  size_t idx = (size_t)hd * (N + 1) + k;
  float Z = wA * Pz[idx] + wB * Qz[idx];
  float num = wA * P[idx * NHID + lane] + wB * Q[idx * NHID + lane];
  float f = num / Z;
  float e = f > 0.f ? f : expf(f) - 1.f;
  xc[(size_t)i * (NHEADS * NHID) + hd * NHID + lane] = e;
}

// ---------------------------------------------------------------------------
// K7: h2 = xc @ Wo  + fused layer-2 scores.
// ---------------------------------------------------------------------------
__global__ __launch_bounds__(256) void k_gemm2(const float* __restrict__ xc,
                                               const float* __restrict__ Wo,
                                               const float* __restrict__ ao,
                                               float* __restrict__ h2,
                                               float* __restrict__ ssrc,
                                               float* __restrict__ sdst) {
  int row = blockIdx.x * 16 + (threadIdx.x >> 4);
  int col = threadIdx.x & 15;
  const float* xr = xc + (size_t)row * (NHEADS * NHID);
  float acc = 0.f;
  for (int k = 0; k < NHEADS * NHID; k += 4) {
    acc += xr[k + 0] * Wo[(k + 0) * NCLASS + col];
    acc += xr[k + 1] * Wo[(k + 1) * NCLASS + col];
    acc += xr[k + 2] * Wo[(k + 2) * NCLASS + col];
    acc += xr[k + 3] * Wo[(k + 3) * NCLASS + col];
  }
  h2[(size_t)row * NCLASS + col] = acc;
  float ps = acc * ao[col], pd = acc * ao[16 + col];
#pragma unroll
  for (int m = 1; m < 16; m <<= 1) { ps += __shfl_xor(ps, m); pd += __shfl_xor(pd, m); }
  if (col == 0) { ssrc[row] = ps; sdst[row] = pd; }
}

// ---------------------------------------------------------------------------
// K8: layer-2 combine + ELU + log_softmax.
// ---------------------------------------------------------------------------
__global__ __launch_bounds__(256) void k_combine2(const float* __restrict__ s_src,
                                                  const float* __restrict__ ts,
                                                  const float* __restrict__ P,
                                                  const float* __restrict__ Q,
                                                  const float* __restrict__ Pz,
                                                  const float* __restrict__ Qz,
                                                  float* __restrict__ out) {
  int i = blockIdx.x * 16 + (threadIdx.x >> 4);
  int c = threadIdx.x & 15;
  float s = s_src[i];
  float key = -s;
  int lo = 0, hi = N;
  while (lo < hi) {
    int mid = (lo + hi) >> 1;
    if (ts[mid] <= key) lo = mid + 1; else hi = mid;
  }
  int k = lo;
  float tm = ts[N - 1];
  float v = s + tm;
  float m = fmaxf(v, ALPHA * v);
  float wA = expf(ALPHA * v - m);
  float wB = expf(v - m);
  float Z = wA * Pz[k] + wB * Qz[k];
  float num = wA * P[(size_t)k * NCLASS + c] + wB * Q[(size_t)k * NCLASS + c];
  float f = num / Z;
  float o = f > 0.f ? f : expf(f) - 1.f;
  float mx = o;
#pragma unroll
  for (int mk = 1; mk < 16; mk <<= 1) mx = fmaxf(mx, __shfl_xor(mx, mk, 16));
  float ex = expf(o - mx);
  float sum = ex;
#pragma unroll
  for (int mk = 1; mk < 16; mk <<= 1) sum += __shfl_xor(sum, mk, 16);
  out[(size_t)i * NCLASS + c] = o - mx - logf(sum);
}

// ---------------------------------------------------------------------------
extern "C" void kernel_launch(void* const* d_in, const int* in_sizes, int n_in,
                              void* d_out, int out_size, void* d_ws, size_t ws_size,
                              hipStream_t stream) {
  const float* x  = (const float*)d_in[0];
  const float* Wh = (const float*)d_in[1];
  const float* ah = (const float*)d_in[2];
  const float* Wo = (const float*)d_in[3];
  const float* ao = (const float*)d_in[4];
  float* out = (float*)d_out;

  char* base = (char*)d_ws;
  size_t off = 0;
  auto alloc_f = [&](size_t n) -> float* {
    float* p = (float*)(base + off);
    off = (off + n * sizeof(float) + 255) & ~(size_t)255;
    return p;
  };
  auto alloc_i = [&](size_t n) -> int* {
    int* p = (int*)(base + off);
    off = (off + n * sizeof(int) + 255) & ~(size_t)255;
    return p;
  };
  auto alloc_u16 = [&](size_t n) -> unsigned short* {
    unsigned short* p = (unsigned short*)(base + off);
    off = (off + n * sizeof(unsigned short) + 255) & ~(size_t)255;
    return p;
  };

  unsigned short* xbf = alloc_u16((size_t)N * NFEAT);
  unsigned short* Wt  = alloc_u16((size_t)NHEADS * NHID * NFEAT);
  float* h1    = alloc_f((size_t)NHEADS * N * NHID);
  float* ssrc1 = alloc_f((size_t)NHEADS * N);
  float* sdst1 = alloc_f((size_t)NHEADS * N);
  float* ts1   = alloc_f((size_t)NHEADS * N);
  int*   perm1 = alloc_i((size_t)NHEADS * N);
  float* csA1  = alloc_f((size_t)NHEADS * NC * NHID);
  float* csB1  = alloc_f((size_t)NHEADS * NC * NHID);
  float* csAz1 = alloc_f(NHEADS * NC);
  float* csBz1 = alloc_f(NHEADS * NC);
  float* P1    = alloc_f((size_t)NHEADS * (N + 1) * NHID);
  float* Q1    = alloc_f((size_t)NHEADS * (N + 1) * NHID);
  float* Pz1   = alloc_f((size_t)NHEADS * (N + 1));
  float* Qz1   = alloc_f((size_t)NHEADS * (N + 1));
  float* xc    = alloc_f((size_t)N * NHEADS * NHID);
  float* h2    = alloc_f((size_t)N * NCLASS);
  float* ssrc2 = alloc_f(N);
  float* sdst2 = alloc_f(N);
  float* ts2   = alloc_f(N);
  int*   perm2 = alloc_i(N);
  float* csA2  = alloc_f((size_t)NC * NCLASS);
  float* csB2  = alloc_f((size_t)NC * NCLASS);
  float* csAz2 = alloc_f(NC);
  float* csBz2 = alloc_f(NC);
  float* P2    = alloc_f((size_t)(N + 1) * NCLASS);
  float* Q2    = alloc_f((size_t)(N + 1) * NCLASS);
  float* Pz2   = alloc_f(N + 1);
  float* Qz2   = alloc_f(N + 1);

  if (off > ws_size) return;

  // ---- pack ----
  hipLaunchKernelGGL(k_pack_x, dim3((N * NFEAT) / 1024), dim3(256), 0, stream, x, xbf);
  hipLaunchKernelGGL(k_pack_w, dim3(NFEAT / 64, NHEADS), dim3(256), 0, stream, Wh, Wt);

  // ---- Layer 1 (8 heads) ----
  hipLaunchKernelGGL(k_gemm_h, dim3(N / 128, NHEADS), dim3(256), 0, stream, xbf, Wt, ah, h1, ssrc1, sdst1);
  hipLaunchKernelGGL(k_rank, dim3(N / 256, NHEADS), dim3(1024), 0, stream, sdst1, ts1, perm1);
  hipLaunchKernelGGL(k_chunksum, dim3(NC / 4, NHEADS), dim3(256), 0, stream, ts1, perm1, h1, csA1, csB1, csAz1, csBz1, NHID);
  hipLaunchKernelGGL(k_chunkscan, dim3(NHEADS), dim3(1024), 0, stream, csA1, csB1, csAz1, csBz1, NHID);
  hipLaunchKernelGGL(k_prefix, dim3(NC / 4, NHEADS), dim3(256), 0, stream, ts1, perm1, h1, csA1, csB1, csAz1, csBz1, P1, Q1, Pz1, Qz1, NHID);
  hipLaunchKernelGGL(k_combine1, dim3(NHEADS * N / 4), dim3(256), 0, stream, ssrc1, ts1, P1, Q1, Pz1, Qz1, xc);

  // ---- Layer 2 ----
  hipLaunchKernelGGL(k_gemm2, dim3(N / 16), dim3(256), 0, stream, xc, Wo, ao, h2, ssrc2, sdst2);
  hipLaunchKernelGGL(k_rank, dim3(N / 256, 1), dim3(1024), 0, stream, sdst2, ts2, perm2);
  hipLaunchKernelGGL(k_chunksum, dim3(NC / 4, 1), dim3(256), 0, stream, ts2, perm2, h2, csA2, csB2, csAz2, csBz2, NCLASS);
  hipLaunchKernelGGL(k_chunkscan, dim3(1), dim3(1024), 0, stream, csA2, csB2, csAz2, csBz2, NCLASS);
  hipLaunchKernelGGL(k_prefix, dim3(NC / 4, 1), dim3(256), 0, stream, ts2, perm2, h2, csA2, csB2, csAz2, csBz2, P2, Q2, Pz2, Qz2, NCLASS);
  hipLaunchKernelGGL(k_combine2, dim3(N / 16), dim3(256), 0, stream, ssrc2, ts2, P2, Q2, Pz2, Qz2, out);
}

// Round 4
// 144.032 us; speedup vs baseline: 2.5460x; 1.2441x over previous
//
#include <hip/hip_runtime.h>
#include <math.h>

#define N 4096
#define NFEAT 512
#define NHID 64
#define NCLASS 16
#define NHEADS 8
#define ALPHA 0.2f
#define NC 256   // chunks per head (16 rows each)

typedef __attribute__((ext_vector_type(8))) short bf16x8;
typedef __attribute__((ext_vector_type(4))) float f32x4;

__device__ inline unsigned short f2bf(float f) {
  unsigned u = __float_as_uint(f);
  unsigned r = u + 0x7fffu + ((u >> 16) & 1u);  // RNE
  return (unsigned short)(r >> 16);
}

// ---------------------------------------------------------------------------
// P0: all packing in one launch.
//   blocks [0,2048):  x fp32 -> bf16
//   blocks [2048,2112): Wt[hd][n][k] = bf16(Wh[hd][k][n])
//   block 2112: Wt2[n][k] = bf16(Wo[k][n])
// ---------------------------------------------------------------------------
__global__ __launch_bounds__(256) void k_pack(const float* __restrict__ x,
                                              const float* __restrict__ Wh,
                                              const float* __restrict__ Wo,
                                              unsigned short* __restrict__ xb,
                                              unsigned short* __restrict__ Wt,
                                              unsigned short* __restrict__ Wt2) {
  int b = blockIdx.x;
  if (b < 2048) {
    int i = (b * 256 + threadIdx.x) * 4;
    float4 v = *(const float4*)(x + i);
    ushort4 o;
    o.x = f2bf(v.x); o.y = f2bf(v.y); o.z = f2bf(v.z); o.w = f2bf(v.w);
    *(ushort4*)(xb + i) = o;
  } else if (b < 2112) {
    int idx = b - 2048;
    int kt = idx & 7, hd = idx >> 3;
    __shared__ float ld[64][65];
    const float* src = Wh + ((size_t)hd * NFEAT + kt * 64) * NHID;
    int r = threadIdx.x >> 2, c0 = (threadIdx.x & 3) * 16;
#pragma unroll
    for (int j = 0; j < 4; ++j) {
      float4 v = *(const float4*)(src + (size_t)r * NHID + c0 + j * 4);
      ld[r][c0 + j * 4 + 0] = v.x; ld[r][c0 + j * 4 + 1] = v.y;
      ld[r][c0 + j * 4 + 2] = v.z; ld[r][c0 + j * 4 + 3] = v.w;
    }
    __syncthreads();
    int n = threadIdx.x >> 2, kq = threadIdx.x & 3;
    unsigned short tmp[16];
#pragma unroll
    for (int j = 0; j < 16; ++j) tmp[j] = f2bf(ld[kq * 16 + j][n]);
    unsigned short* dst = Wt + ((size_t)hd * 64 + n) * NFEAT + kt * 64 + kq * 16;
    ((uint4*)dst)[0] = *(uint4*)tmp;
    ((uint4*)dst)[1] = *(uint4*)(tmp + 8);
  } else {
    for (int e = threadIdx.x; e < NFEAT * NCLASS; e += 256) {
      int n = e & 15, k = e >> 4;
      Wt2[(size_t)n * NFEAT + k] = f2bf(Wo[(size_t)k * NCLASS + n]);
    }
  }
}

// ---------------------------------------------------------------------------
// K1: MFMA bf16 GEMM h = x @ Wh per head (M=4096,K=512,N=64), 128x64 tile,
// 4 waves (2M x 2N), fused score epilogue (s_src/s_dst).
// ---------------------------------------------------------------------------
__global__ __launch_bounds__(256) void k_gemm_h(const unsigned short* __restrict__ xb,
                                                const unsigned short* __restrict__ Wt,
                                                const float* __restrict__ ah,
                                                float* __restrict__ h,
                                                float* __restrict__ ssrc,
                                                float* __restrict__ sdst) {
  const int hd = blockIdx.y;
  const int i0 = blockIdx.x * 128;
  const int t = threadIdx.x;
  const int w = t >> 6, lane = t & 63;
  const int lr = lane & 15, kg = lane >> 4;
  const int wm = (w & 1) * 64, wn = (w >> 1) * 32;
  __shared__ uint4 Als[128][4];  // 128 rows x 32 bf16, unit-swizzled
  __shared__ uint4 Bls[64][4];
  __shared__ float sredS[128][2];
  __shared__ float sredD[128][2];
  const unsigned short* xrow = xb + (size_t)i0 * NFEAT;
  const unsigned short* wrow = Wt + (size_t)hd * 64 * NFEAT;

  f32x4 acc[4][2];
#pragma unroll
  for (int a = 0; a < 4; ++a)
#pragma unroll
    for (int b = 0; b < 2; ++b) acc[a][b] = (f32x4){0.f, 0.f, 0.f, 0.f};

  const int ra = t >> 1, ua = (t & 1) * 2;   // A staging: row, first unit
  const int rb = t >> 2, ub = t & 3;         // B staging: row(n), unit
  for (int k0 = 0; k0 < NFEAT; k0 += 32) {
    uint4 qa0 = *(const uint4*)(xrow + (size_t)ra * NFEAT + k0 + ua * 8);
    uint4 qa1 = *(const uint4*)(xrow + (size_t)ra * NFEAT + k0 + ua * 8 + 8);
    uint4 qb  = *(const uint4*)(wrow + (size_t)rb * NFEAT + k0 + ub * 8);
    Als[ra][(ua) ^ (ra & 3)] = qa0;
    Als[ra][(ua + 1) ^ (ra & 3)] = qa1;
    Bls[rb][ub ^ (rb & 3)] = qb;
    __syncthreads();
    bf16x8 af[4], bfv[2];
#pragma unroll
    for (int mb = 0; mb < 4; ++mb) {
      int row = wm + mb * 16 + lr;
      af[mb] = __builtin_bit_cast(bf16x8, Als[row][kg ^ (row & 3)]);
    }
#pragma unroll
    for (int nb = 0; nb < 2; ++nb) {
      int col = wn + nb * 16 + lr;
      bfv[nb] = __builtin_bit_cast(bf16x8, Bls[col][kg ^ (col & 3)]);
    }
#pragma unroll
    for (int mb = 0; mb < 4; ++mb)
#pragma unroll
      for (int nb = 0; nb < 2; ++nb)
        acc[mb][nb] = __builtin_amdgcn_mfma_f32_16x16x32_bf16(af[mb], bfv[nb], acc[mb][nb], 0, 0, 0);
    __syncthreads();
  }

  // write h (fp32)
  float* hout = h + ((size_t)hd * N + i0) * NHID;
#pragma unroll
  for (int mb = 0; mb < 4; ++mb)
#pragma unroll
    for (int nb = 0; nb < 2; ++nb) {
      int rbase = wm + mb * 16 + kg * 4;
      int col = wn + nb * 16 + lr;
#pragma unroll
      for (int reg = 0; reg < 4; ++reg)
        hout[(size_t)(rbase + reg) * NHID + col] = acc[mb][nb][reg];
    }

  // fused scores: s_src = h . ah[:64], s_dst = h . ah[64:]
  float aS[2], aD[2];
#pragma unroll
  for (int nb = 0; nb < 2; ++nb) {
    aS[nb] = ah[hd * 128 + wn + nb * 16 + lr];
    aD[nb] = ah[hd * 128 + 64 + wn + nb * 16 + lr];
  }
#pragma unroll
  for (int mb = 0; mb < 4; ++mb)
#pragma unroll
    for (int reg = 0; reg < 4; ++reg) {
      float ps = acc[mb][0][reg] * aS[0] + acc[mb][1][reg] * aS[1];
      float pd = acc[mb][0][reg] * aD[0] + acc[mb][1][reg] * aD[1];
#pragma unroll
      for (int m = 1; m < 16; m <<= 1) { ps += __shfl_xor(ps, m); pd += __shfl_xor(pd, m); }
      if (lr == 0) {
        int rl = wm + mb * 16 + kg * 4 + reg;
        sredS[rl][w >> 1] = ps;
        sredD[rl][w >> 1] = pd;
      }
    }
  __syncthreads();
  if (t < 128) {
    ssrc[(size_t)hd * N + i0 + t] = sredS[t][0] + sredS[t][1];
    sdst[(size_t)hd * N + i0 + t] = sredD[t][0] + sredD[t][1];
  }
}

// ---------------------------------------------------------------------------
// K4: counting rank. u32 keys: monotone-float top-20 bits | index (unique ->
// bijective scatter; order deviation vs exact sort <= 5e-4 relative, harmless
// downstream). JT j's per block, 1024/JT segments of N*JT/1024 stream elems.
// ---------------------------------------------------------------------------
template <int JT>
__global__ __launch_bounds__(1024) void k_rank(const float* __restrict__ t,
                                               float* __restrict__ ts,
                                               int* __restrict__ perm) {
  const int SEGS = 1024 / JT;
  const int SEGLEN = N / SEGS;
  int hd = blockIdx.y;
  int tid = threadIdx.x;
  int jl = tid % JT;
  int seg = tid / JT;
  int j = blockIdx.x * JT + jl;
  __shared__ unsigned skey[N];
  __shared__ int scnt[JT];
  const float* th = t + (size_t)hd * N;
  for (int i = tid; i < N; i += 1024) {
    unsigned u = __float_as_uint(th[i]);
    u = (u & 0x80000000u) ? ~u : (u | 0x80000000u);
    skey[i] = (u & 0xFFFFF000u) | (unsigned)i;
  }
  if (tid < JT) scnt[tid] = 0;
  __syncthreads();
  unsigned kj = skey[j];
  int cnt = 0;
  const int l0 = seg * SEGLEN;
#pragma unroll 16
  for (int l = 0; l < SEGLEN; ++l) cnt += (skey[l0 + l] < kj) ? 1 : 0;
  atomicAdd(&scnt[jl], cnt);
  __syncthreads();
  if (seg == 0) {
    int r = scnt[jl];
    ts[(size_t)hd * N + r] = th[j];
    perm[(size_t)hd * N + r] = j;
  }
}

// ---------------------------------------------------------------------------
// K5a: per-chunk (16 rows) sums of eA*g and eB*g. One wave per chunk.
// ---------------------------------------------------------------------------
__global__ __launch_bounds__(256) void k_chunksum(const float* __restrict__ ts,
                                                  const int* __restrict__ perm,
                                                  const float* __restrict__ h,
                                                  float* __restrict__ csA,
                                                  float* __restrict__ csB,
                                                  float* __restrict__ csAz,
                                                  float* __restrict__ csBz,
                                                  int F) {
  int hd = blockIdx.y, lane = threadIdx.x & 63;
  int c = blockIdx.x * 4 + (threadIdx.x >> 6);
  int r0 = c * 16;
  float tm = ts[(size_t)hd * N + N - 1];
  float sA = 0.f, sB = 0.f, sAz = 0.f, sBz = 0.f;
  for (int r = 0; r < 16; ++r) {
    float tv = ts[(size_t)hd * N + r0 + r];
    int p = perm[(size_t)hd * N + r0 + r];
    float eA = expf(ALPHA * (tv - tm));
    float eB = expf(tv - tm);
    float hv = (lane < F) ? h[((size_t)hd * N + p) * F + lane] : 0.f;
    sA += eA * hv; sB += eB * hv;
    sAz += eA; sBz += eB;
  }
  if (lane < F) {
    csA[((size_t)hd * NC + c) * F + lane] = sA;
    csB[((size_t)hd * NC + c) * F + lane] = sB;
  }
  if (lane == 0) { csAz[hd * NC + c] = sAz; csBz[hd * NC + c] = sBz; }
}

// ---------------------------------------------------------------------------
// K5b: exclusive scan of 256 chunk sums per head (A ascending, B suffix).
// One 1024-thread block per head; thread=(lane=F-dim, g=16-chunk group).
// ---------------------------------------------------------------------------
__global__ __launch_bounds__(1024) void k_chunkscan(float* __restrict__ csA,
                                                    float* __restrict__ csB,
                                                    float* __restrict__ csAz,
                                                    float* __restrict__ csBz,
                                                    int F) {
  int hd = blockIdx.x;
  int t = threadIdx.x, lane = t & 63, g = t >> 6;
  __shared__ float part[16][64];
  __shared__ float partz[16];
  size_t b0 = ((size_t)hd * NC + g * 16) * F;
  float sA = 0.f, sB = 0.f, sAz = 0.f, sBz = 0.f;
  if (lane < F) {
#pragma unroll 4
    for (int j = 0; j < 16; ++j) sA += csA[b0 + (size_t)j * F + lane];
#pragma unroll 4
    for (int j = 0; j < 16; ++j) sB += csB[b0 + (size_t)j * F + lane];
  }
  if (lane == 0) {
    for (int j = 0; j < 16; ++j) { sAz += csAz[hd * NC + g * 16 + j]; sBz += csBz[hd * NC + g * 16 + j]; }
  }
  if (lane < F) part[g][lane] = sA;
  if (lane == 0) partz[g] = sAz;
  __syncthreads();
  float baseA = 0.f, baseAz = 0.f;
  if (lane < F) for (int g2 = 0; g2 < g; ++g2) baseA += part[g2][lane];
  if (lane == 0) for (int g2 = 0; g2 < g; ++g2) baseAz += partz[g2];
  __syncthreads();
  if (lane < F) part[g][lane] = sB;
  if (lane == 0) partz[g] = sBz;
  __syncthreads();
  float baseB = 0.f, baseBz = 0.f;
  if (lane < F) for (int g2 = g + 1; g2 < 16; ++g2) baseB += part[g2][lane];
  if (lane == 0) for (int g2 = g + 1; g2 < 16; ++g2) baseBz += partz[g2];
  if (lane < F) {
    float run = baseA;
    for (int j = 0; j < 16; ++j) {
      size_t o = b0 + (size_t)j * F + lane;
      float tmp = csA[o]; csA[o] = run; run += tmp;
    }
    run = baseB;
    for (int j = 15; j >= 0; --j) {
      size_t o = b0 + (size_t)j * F + lane;
      float tmp = csB[o]; csB[o] = run; run += tmp;
    }
  }
  if (lane == 0) {
    float run = baseAz;
    for (int j = 0; j < 16; ++j) {
      int o = hd * NC + g * 16 + j;
      float tmp = csAz[o]; csAz[o] = run; run += tmp;
    }
    run = baseBz;
    for (int j = 15; j >= 0; --j) {
      int o = hd * NC + g * 16 + j;
      float tmp = csBz[o]; csBz[o] = run; run += tmp;
    }
  }
}

// ---------------------------------------------------------------------------
// K5c: fill P (exclusive ascending prefix of eA*g) and Q (suffix of eB*g).
// One wave per 16-row chunk.
// ---------------------------------------------------------------------------
__global__ __launch_bounds__(256) void k_prefix(const float* __restrict__ ts,
                                                const int* __restrict__ perm,
                                                const float* __restrict__ h,
                                                const float* __restrict__ csA,
                                                const float* __restrict__ csB,
                                                const float* __restrict__ csAz,
                                                const float* __restrict__ csBz,
                                                float* __restrict__ P,
                                                float* __restrict__ Q,
                                                float* __restrict__ Pz,
                                                float* __restrict__ Qz,
                                                int F) {
  int hd = blockIdx.y, lane = threadIdx.x & 63;
  int c = blockIdx.x * 4 + (threadIdx.x >> 6);
  int r0 = c * 16;
  float tm = ts[(size_t)hd * N + N - 1];
  size_t base = (size_t)hd * (N + 1);
  float accA = (lane < F) ? csA[((size_t)hd * NC + c) * F + lane] : 0.f;
  float accAz = csAz[hd * NC + c];
  for (int r = 0; r < 16; ++r) {
    int row = r0 + r;
    float tv = ts[(size_t)hd * N + row];
    int p = perm[(size_t)hd * N + row];
    float eA = expf(ALPHA * (tv - tm));
    float hv = (lane < F) ? h[((size_t)hd * N + p) * F + lane] : 0.f;
    if (lane < F) P[(base + row) * F + lane] = accA;
    if (lane == 0) Pz[base + row] = accAz;
    accA += eA * hv;
    accAz += eA;
  }
  if (c == NC - 1) {
    if (lane < F) { P[(base + N) * F + lane] = accA; Q[(base + N) * F + lane] = 0.f; }
    if (lane == 0) { Pz[base + N] = accAz; Qz[base + N] = 0.f; }
  }
  float accB = (lane < F) ? csB[((size_t)hd * NC + c) * F + lane] : 0.f;
  float accBz = csBz[hd * NC + c];
  for (int r = 15; r >= 0; --r) {
    int row = r0 + r;
    float tv = ts[(size_t)hd * N + row];
    int p = perm[(size_t)hd * N + row];
    float eB = expf(tv - tm);
    float hv = (lane < F) ? h[((size_t)hd * N + p) * F + lane] : 0.f;
    accB += eB * hv;
    accBz += eB;
    if (lane < F) Q[(base + row) * F + lane] = accB;
    if (lane == 0) Qz[base + row] = accBz;
  }
}

// ---------------------------------------------------------------------------
// K6: layer-1 combine (binary-search split, blend, ELU). Writes xc as bf16
// (head-major concat) for the MFMA layer-2 GEMM.
// ---------------------------------------------------------------------------
__global__ __launch_bounds__(256) void k_combine1(const float* __restrict__ s_src,
                                                  const float* __restrict__ ts,
                                                  const float* __restrict__ P,
                                                  const float* __restrict__ Q,
                                                  const float* __restrict__ Pz,
                                                  const float* __restrict__ Qz,
                                                  unsigned short* __restrict__ xcb) {
  int wid = (blockIdx.x * 256 + threadIdx.x) >> 6;
  int lane = threadIdx.x & 63;
  int hd = wid / N, i = wid % N;
  float s = s_src[wid];
  float key = -s;
  const float* tsh = ts + (size_t)hd * N;
  int lo = 0, hi = N;
  while (lo < hi) {
    int mid = (lo + hi) >> 1;
    if (tsh[mid] <= key) lo = mid + 1; else hi = mid;
  }
  int k = lo;
  float tm = tsh[N - 1];
  float v = s + tm;
  float m = fmaxf(v, ALPHA * v);
  float wA = expf(ALPHA * v - m);
  float wB = expf(v - m);
  size_t idx = (size_t)hd * (N + 1) + k;
  float Z = wA * Pz[idx] + wB * Qz[idx];
  float num = wA * P[idx * NHID + lane] + wB * Q[idx * NHID + lane];
  float f = num / Z;
  float e = f > 0.f ? f : expf(f) - 1.f;
  xcb[(size_t)i * (NHEADS * NHID) + hd * NHID + lane] = f2bf(e);
}

// ---------------------------------------------------------------------------
// K7: h2 = xc @ Wo via MFMA (M=4096, N=16, K=512) + fused layer-2 scores.
// Block = 4 waves, each wave a 16-row tile; B streamed from L2-hot Wt2.
// ---------------------------------------------------------------------------
__global__ __launch_bounds__(256) void k_gemm2(const unsigned short* __restrict__ xcb,
                                               const unsigned short* __restrict__ Wt2,
                                               const float* __restrict__ ao,
                                               float* __restrict__ h2,
                                               float* __restrict__ ssrc,
                                               float* __restrict__ sdst) {
  const int t = threadIdx.x;
  const int w = t >> 6, lane = t & 63;
  const int lr = lane & 15, kg = lane >> 4;
  const int i0 = blockIdx.x * 64 + w * 16;
  f32x4 acc = (f32x4){0.f, 0.f, 0.f, 0.f};
  const unsigned short* arow = xcb + (size_t)(i0 + lr) * NFEAT;
  const unsigned short* brow = Wt2 + (size_t)lr * NFEAT;
#pragma unroll
  for (int k0 = 0; k0 < NFEAT; k0 += 32) {
    bf16x8 af = __builtin_bit_cast(bf16x8, *(const uint4*)(arow + k0 + kg * 8));
    bf16x8 bf = __builtin_bit_cast(bf16x8, *(const uint4*)(brow + k0 + kg * 8));
    acc = __builtin_amdgcn_mfma_f32_16x16x32_bf16(af, bf, acc, 0, 0, 0);
  }
  float aS = ao[lr], aD = ao[16 + lr];
#pragma unroll
  for (int reg = 0; reg < 4; ++reg) {
    int row = i0 + kg * 4 + reg;
    h2[(size_t)row * NCLASS + lr] = acc[reg];
    float ps = acc[reg] * aS, pd = acc[reg] * aD;
#pragma unroll
    for (int m = 1; m < 16; m <<= 1) { ps += __shfl_xor(ps, m); pd += __shfl_xor(pd, m); }
    if (lr == 0) { ssrc[row] = ps; sdst[row] = pd; }
  }
}

// ---------------------------------------------------------------------------
// K8: layer-2 combine + ELU + log_softmax.
// ---------------------------------------------------------------------------
__global__ __launch_bounds__(256) void k_combine2(const float* __restrict__ s_src,
                                                  const float* __restrict__ ts,
                                                  const float* __restrict__ P,
                                                  const float* __restrict__ Q,
                                                  const float* __restrict__ Pz,
                                                  const float* __restrict__ Qz,
                                                  float* __restrict__ out) {
  int i = blockIdx.x * 16 + (threadIdx.x >> 4);
  int c = threadIdx.x & 15;
  float s = s_src[i];
  float key = -s;
  int lo = 0, hi = N;
  while (lo < hi) {
    int mid = (lo + hi) >> 1;
    if (ts[mid] <= key) lo = mid + 1; else hi = mid;
  }
  int k = lo;
  float tm = ts[N - 1];
  float v = s + tm;
  float m = fmaxf(v, ALPHA * v);
  float wA = expf(ALPHA * v - m);
  float wB = expf(v - m);
  float Z = wA * Pz[k] + wB * Qz[k];
  float num = wA * P[(size_t)k * NCLASS + c] + wB * Q[(size_t)k * NCLASS + c];
  float f = num / Z;
  float o = f > 0.f ? f : expf(f) - 1.f;
  float mx = o;
#pragma unroll
  for (int mk = 1; mk < 16; mk <<= 1) mx = fmaxf(mx, __shfl_xor(mx, mk, 16));
  float ex = expf(o - mx);
  float sum = ex;
#pragma unroll
  for (int mk = 1; mk < 16; mk <<= 1) sum += __shfl_xor(sum, mk, 16);
  out[(size_t)i * NCLASS + c] = o - mx - logf(sum);
}

// ---------------------------------------------------------------------------
extern "C" void kernel_launch(void* const* d_in, const int* in_sizes, int n_in,
                              void* d_out, int out_size, void* d_ws, size_t ws_size,
                              hipStream_t stream) {
  const float* x  = (const float*)d_in[0];
  const float* Wh = (const float*)d_in[1];
  const float* ah = (const float*)d_in[2];
  const float* Wo = (const float*)d_in[3];
  const float* ao = (const float*)d_in[4];
  float* out = (float*)d_out;

  char* base = (char*)d_ws;
  size_t off = 0;
  auto alloc_f = [&](size_t n) -> float* {
    float* p = (float*)(base + off);
    off = (off + n * sizeof(float) + 255) & ~(size_t)255;
    return p;
  };
  auto alloc_i = [&](size_t n) -> int* {
    int* p = (int*)(base + off);
    off = (off + n * sizeof(int) + 255) & ~(size_t)255;
    return p;
  };
  auto alloc_u16 = [&](size_t n) -> unsigned short* {
    unsigned short* p = (unsigned short*)(base + off);
    off = (off + n * sizeof(unsigned short) + 255) & ~(size_t)255;
    return p;
  };

  unsigned short* xbf = alloc_u16((size_t)N * NFEAT);
  unsigned short* Wt  = alloc_u16((size_t)NHEADS * NHID * NFEAT);
  unsigned short* Wt2 = alloc_u16((size_t)NCLASS * NFEAT);
  float* h1    = alloc_f((size_t)NHEADS * N * NHID);
  float* ssrc1 = alloc_f((size_t)NHEADS * N);
  float* sdst1 = alloc_f((size_t)NHEADS * N);
  float* ts1   = alloc_f((size_t)NHEADS * N);
  int*   perm1 = alloc_i((size_t)NHEADS * N);
  float* csA1  = alloc_f((size_t)NHEADS * NC * NHID);
  float* csB1  = alloc_f((size_t)NHEADS * NC * NHID);
  float* csAz1 = alloc_f(NHEADS * NC);
  float* csBz1 = alloc_f(NHEADS * NC);
  float* P1    = alloc_f((size_t)NHEADS * (N + 1) * NHID);
  float* Q1    = alloc_f((size_t)NHEADS * (N + 1) * NHID);
  float* Pz1   = alloc_f((size_t)NHEADS * (N + 1));
  float* Qz1   = alloc_f((size_t)NHEADS * (N + 1));
  unsigned short* xcb = alloc_u16((size_t)N * NHEADS * NHID);
  float* h2    = alloc_f((size_t)N * NCLASS);
  float* ssrc2 = alloc_f(N);
  float* sdst2 = alloc_f(N);
  float* ts2   = alloc_f(N);
  int*   perm2 = alloc_i(N);
  float* csA2  = alloc_f((size_t)NC * NCLASS);
  float* csB2  = alloc_f((size_t)NC * NCLASS);
  float* csAz2 = alloc_f(NC);
  float* csBz2 = alloc_f(NC);
  float* P2    = alloc_f((size_t)(N + 1) * NCLASS);
  float* Q2    = alloc_f((size_t)(N + 1) * NCLASS);
  float* Pz2   = alloc_f(N + 1);
  float* Qz2   = alloc_f(N + 1);

  if (off > ws_size) return;

  // ---- pack (x, Wh, Wo) ----
  hipLaunchKernelGGL(k_pack, dim3(2113), dim3(256), 0, stream, x, Wh, Wo, xbf, Wt, Wt2);

  // ---- Layer 1 (8 heads) ----
  hipLaunchKernelGGL(k_gemm_h, dim3(N / 128, NHEADS), dim3(256), 0, stream, xbf, Wt, ah, h1, ssrc1, sdst1);
  hipLaunchKernelGGL(k_rank<128>, dim3(N / 128, NHEADS), dim3(1024), 0, stream, sdst1, ts1, perm1);
  hipLaunchKernelGGL(k_chunksum, dim3(NC / 4, NHEADS), dim3(256), 0, stream, ts1, perm1, h1, csA1, csB1, csAz1, csBz1, NHID);
  hipLaunchKernelGGL(k_chunkscan, dim3(NHEADS), dim3(1024), 0, stream, csA1, csB1, csAz1, csBz1, NHID);
  hipLaunchKernelGGL(k_prefix, dim3(NC / 4, NHEADS), dim3(256), 0, stream, ts1, perm1, h1, csA1, csB1, csAz1, csBz1, P1, Q1, Pz1, Qz1, NHID);
  hipLaunchKernelGGL(k_combine1, dim3(NHEADS * N / 4), dim3(256), 0, stream, ssrc1, ts1, P1, Q1, Pz1, Qz1, xcb);

  // ---- Layer 2 ----
  hipLaunchKernelGGL(k_gemm2, dim3(N / 64), dim3(256), 0, stream, xcb, Wt2, ao, h2, ssrc2, sdst2);
  hipLaunchKernelGGL(k_rank<32>, dim3(N / 32, 1), dim3(1024), 0, stream, sdst2, ts2, perm2);
  hipLaunchKernelGGL(k_chunksum, dim3(NC / 4, 1), dim3(256), 0, stream, ts2, perm2, h2, csA2, csB2, csAz2, csBz2, NCLASS);
  hipLaunchKernelGGL(k_chunkscan, dim3(1), dim3(1024), 0, stream, csA2, csB2, csAz2, csBz2, NCLASS);
  hipLaunchKernelGGL(k_prefix, dim3(NC / 4, 1), dim3(256), 0, stream, ts2, perm2, h2, csA2, csB2, csAz2, csBz2, P2, Q2, Pz2, Qz2, NCLASS);
  hipLaunchKernelGGL(k_combine2, dim3(N / 16), dim3(256), 0, stream, ssrc2, ts2, P2, Q2, Pz2, Qz2, out);
}

// Round 5
// 141.342 us; speedup vs baseline: 2.5944x; 1.0190x over previous
//
#include <hip/hip_runtime.h>
#include <math.h>

#define N 4096
#define NFEAT 512
#define NHID 64
#define NCLASS 16
#define NHEADS 8
#define ALPHA 0.2f
#define NC 256   // chunks per head (16 rows each)

typedef __attribute__((ext_vector_type(8))) short bf16x8;
typedef __attribute__((ext_vector_type(4))) float f32x4;

__device__ inline unsigned short f2bf(float f) {
  unsigned u = __float_as_uint(f);
  unsigned r = u + 0x7fffu + ((u >> 16) & 1u);  // RNE
  return (unsigned short)(r >> 16);
}

// ---------------------------------------------------------------------------
// P0: all packing in one launch.
//   blocks [0,2048):  x fp32 -> bf16
//   blocks [2048,2112): Wt[hd][n][k] = bf16(Wh[hd][k][n])
//   block 2112: Wt2[n][k] = bf16(Wo[k][n])
// ---------------------------------------------------------------------------
__global__ __launch_bounds__(256) void k_pack(const float* __restrict__ x,
                                              const float* __restrict__ Wh,
                                              const float* __restrict__ Wo,
                                              unsigned short* __restrict__ xb,
                                              unsigned short* __restrict__ Wt,
                                              unsigned short* __restrict__ Wt2) {
  int b = blockIdx.x;
  if (b < 2048) {
    int i = (b * 256 + threadIdx.x) * 4;
    float4 v = *(const float4*)(x + i);
    ushort4 o;
    o.x = f2bf(v.x); o.y = f2bf(v.y); o.z = f2bf(v.z); o.w = f2bf(v.w);
    *(ushort4*)(xb + i) = o;
  } else if (b < 2112) {
    int idx = b - 2048;
    int kt = idx & 7, hd = idx >> 3;
    __shared__ float ld[64][65];
    const float* src = Wh + ((size_t)hd * NFEAT + kt * 64) * NHID;
    int r = threadIdx.x >> 2, c0 = (threadIdx.x & 3) * 16;
#pragma unroll
    for (int j = 0; j < 4; ++j) {
      float4 v = *(const float4*)(src + (size_t)r * NHID + c0 + j * 4);
      ld[r][c0 + j * 4 + 0] = v.x; ld[r][c0 + j * 4 + 1] = v.y;
      ld[r][c0 + j * 4 + 2] = v.z; ld[r][c0 + j * 4 + 3] = v.w;
    }
    __syncthreads();
    int n = threadIdx.x >> 2, kq = threadIdx.x & 3;
    unsigned short tmp[16];
#pragma unroll
    for (int j = 0; j < 16; ++j) tmp[j] = f2bf(ld[kq * 16 + j][n]);
    unsigned short* dst = Wt + ((size_t)hd * 64 + n) * NFEAT + kt * 64 + kq * 16;
    ((uint4*)dst)[0] = *(uint4*)tmp;
    ((uint4*)dst)[1] = *(uint4*)(tmp + 8);
  } else {
    for (int e = threadIdx.x; e < NFEAT * NCLASS; e += 256) {
      int n = e & 15, k = e >> 4;
      Wt2[(size_t)n * NFEAT + k] = f2bf(Wo[(size_t)k * NCLASS + n]);
    }
  }
}

// ---------------------------------------------------------------------------
// K1: MFMA bf16 GEMM h = x @ Wh per head (M=4096,K=512,N=64), 128x64 tile,
// 4 waves (2M x 2N), fused score epilogue (s_src/s_dst).
// ---------------------------------------------------------------------------
__global__ __launch_bounds__(256) void k_gemm_h(const unsigned short* __restrict__ xb,
                                                const unsigned short* __restrict__ Wt,
                                                const float* __restrict__ ah,
                                                float* __restrict__ h,
                                                float* __restrict__ ssrc,
                                                float* __restrict__ sdst) {
  const int hd = blockIdx.y;
  const int i0 = blockIdx.x * 128;
  const int t = threadIdx.x;
  const int w = t >> 6, lane = t & 63;
  const int lr = lane & 15, kg = lane >> 4;
  const int wm = (w & 1) * 64, wn = (w >> 1) * 32;
  __shared__ uint4 Als[128][4];  // 128 rows x 32 bf16, unit-swizzled
  __shared__ uint4 Bls[64][4];
  __shared__ float sredS[128][2];
  __shared__ float sredD[128][2];
  const unsigned short* xrow = xb + (size_t)i0 * NFEAT;
  const unsigned short* wrow = Wt + (size_t)hd * 64 * NFEAT;

  f32x4 acc[4][2];
#pragma unroll
  for (int a = 0; a < 4; ++a)
#pragma unroll
    for (int b = 0; b < 2; ++b) acc[a][b] = (f32x4){0.f, 0.f, 0.f, 0.f};

  const int ra = t >> 1, ua = (t & 1) * 2;   // A staging: row, first unit
  const int rb = t >> 2, ub = t & 3;         // B staging: row(n), unit
  for (int k0 = 0; k0 < NFEAT; k0 += 32) {
    uint4 qa0 = *(const uint4*)(xrow + (size_t)ra * NFEAT + k0 + ua * 8);
    uint4 qa1 = *(const uint4*)(xrow + (size_t)ra * NFEAT + k0 + ua * 8 + 8);
    uint4 qb  = *(const uint4*)(wrow + (size_t)rb * NFEAT + k0 + ub * 8);
    Als[ra][(ua) ^ (ra & 3)] = qa0;
    Als[ra][(ua + 1) ^ (ra & 3)] = qa1;
    Bls[rb][ub ^ (rb & 3)] = qb;
    __syncthreads();
    bf16x8 af[4], bfv[2];
#pragma unroll
    for (int mb = 0; mb < 4; ++mb) {
      int row = wm + mb * 16 + lr;
      af[mb] = __builtin_bit_cast(bf16x8, Als[row][kg ^ (row & 3)]);
    }
#pragma unroll
    for (int nb = 0; nb < 2; ++nb) {
      int col = wn + nb * 16 + lr;
      bfv[nb] = __builtin_bit_cast(bf16x8, Bls[col][kg ^ (col & 3)]);
    }
#pragma unroll
    for (int mb = 0; mb < 4; ++mb)
#pragma unroll
      for (int nb = 0; nb < 2; ++nb)
        acc[mb][nb] = __builtin_amdgcn_mfma_f32_16x16x32_bf16(af[mb], bfv[nb], acc[mb][nb], 0, 0, 0);
    __syncthreads();
  }

  // write h (fp32)
  float* hout = h + ((size_t)hd * N + i0) * NHID;
#pragma unroll
  for (int mb = 0; mb < 4; ++mb)
#pragma unroll
    for (int nb = 0; nb < 2; ++nb) {
      int rbase = wm + mb * 16 + kg * 4;
      int col = wn + nb * 16 + lr;
#pragma unroll
      for (int reg = 0; reg < 4; ++reg)
        hout[(size_t)(rbase + reg) * NHID + col] = acc[mb][nb][reg];
    }

  // fused scores: s_src = h . ah[:64], s_dst = h . ah[64:]
  float aS[2], aD[2];
#pragma unroll
  for (int nb = 0; nb < 2; ++nb) {
    aS[nb] = ah[hd * 128 + wn + nb * 16 + lr];
    aD[nb] = ah[hd * 128 + 64 + wn + nb * 16 + lr];
  }
#pragma unroll
  for (int mb = 0; mb < 4; ++mb)
#pragma unroll
    for (int reg = 0; reg < 4; ++reg) {
      float ps = acc[mb][0][reg] * aS[0] + acc[mb][1][reg] * aS[1];
      float pd = acc[mb][0][reg] * aD[0] + acc[mb][1][reg] * aD[1];
#pragma unroll
      for (int m = 1; m < 16; m <<= 1) { ps += __shfl_xor(ps, m); pd += __shfl_xor(pd, m); }
      if (lr == 0) {
        int rl = wm + mb * 16 + kg * 4 + reg;
        sredS[rl][w >> 1] = ps;
        sredD[rl][w >> 1] = pd;
      }
    }
  __syncthreads();
  if (t < 128) {
    ssrc[(size_t)hd * N + i0 + t] = sredS[t][0] + sredS[t][1];
    sdst[(size_t)hd * N + i0 + t] = sredD[t][0] + sredD[t][1];
  }
}

// ---------------------------------------------------------------------------
// K4: ballot counting rank. u32 keys (monotone top-20 float bits | index).
// Wave owns 16 j's; scans all N keys 64/lane-step; cnt += popc(ballot(<)).
// grid (64, heads), 256 threads.
// ---------------------------------------------------------------------------
__global__ __launch_bounds__(256) void k_rank(const float* __restrict__ t,
                                              float* __restrict__ ts,
                                              int* __restrict__ perm) {
  int hd = blockIdx.y;
  const float* th = t + (size_t)hd * N;
  __shared__ unsigned skey[N];
  int tid = threadIdx.x;
  for (int i = tid; i < N; i += 256) {
    unsigned u = __float_as_uint(th[i]);
    u = (u & 0x80000000u) ? ~u : (u | 0x80000000u);
    skey[i] = (u & 0xFFFFF000u) | (unsigned)i;
  }
  __syncthreads();
  int wv = tid >> 6, lane = tid & 63;
  int jbase = blockIdx.x * 64 + wv * 16;
  unsigned kj[16];
#pragma unroll
  for (int jj = 0; jj < 16; ++jj) kj[jj] = skey[jbase + jj];
  int cnt[16];
#pragma unroll
  for (int jj = 0; jj < 16; ++jj) cnt[jj] = 0;
  for (int c = 0; c < N; c += 64) {
    unsigned key = skey[c + lane];
#pragma unroll
    for (int jj = 0; jj < 16; ++jj)
      cnt[jj] += __popcll(__ballot(key < kj[jj]));
  }
  int myc = 0;
#pragma unroll
  for (int jj = 0; jj < 16; ++jj) if (lane == jj) myc = cnt[jj];
  if (lane < 16) {
    int j = jbase + lane;
    ts[(size_t)hd * N + myc] = th[j];
    perm[(size_t)hd * N + myc] = j;
  }
}

// ---------------------------------------------------------------------------
// K5a: per-chunk (16 rows) sums of eA*g and eB*g. One wave per chunk.
// ---------------------------------------------------------------------------
__global__ __launch_bounds__(256) void k_chunksum(const float* __restrict__ ts,
                                                  const int* __restrict__ perm,
                                                  const float* __restrict__ h,
                                                  float* __restrict__ csA,
                                                  float* __restrict__ csB,
                                                  float* __restrict__ csAz,
                                                  float* __restrict__ csBz,
                                                  int F) {
  int hd = blockIdx.y, lane = threadIdx.x & 63;
  int c = blockIdx.x * 4 + (threadIdx.x >> 6);
  int r0 = c * 16;
  float tm = ts[(size_t)hd * N + N - 1];
  float sA = 0.f, sB = 0.f, sAz = 0.f, sBz = 0.f;
  for (int r = 0; r < 16; ++r) {
    float tv = ts[(size_t)hd * N + r0 + r];
    int p = perm[(size_t)hd * N + r0 + r];
    float eA = expf(ALPHA * (tv - tm));
    float eB = expf(tv - tm);
    float hv = (lane < F) ? h[((size_t)hd * N + p) * F + lane] : 0.f;
    sA += eA * hv; sB += eB * hv;
    sAz += eA; sBz += eB;
  }
  if (lane < F) {
    csA[((size_t)hd * NC + c) * F + lane] = sA;
    csB[((size_t)hd * NC + c) * F + lane] = sB;
  }
  if (lane == 0) { csAz[hd * NC + c] = sAz; csBz[hd * NC + c] = sBz; }
}

// ---------------------------------------------------------------------------
// K5b: exclusive scan of 256 chunk sums per head (A ascending, B suffix).
// One 1024-thread block per head; thread=(lane=F-dim, g=16-chunk group).
// ---------------------------------------------------------------------------
__global__ __launch_bounds__(1024) void k_chunkscan(float* __restrict__ csA,
                                                    float* __restrict__ csB,
                                                    float* __restrict__ csAz,
                                                    float* __restrict__ csBz,
                                                    int F) {
  int hd = blockIdx.x;
  int t = threadIdx.x, lane = t & 63, g = t >> 6;
  __shared__ float part[16][64];
  __shared__ float partz[16];
  size_t b0 = ((size_t)hd * NC + g * 16) * F;
  float sA = 0.f, sB = 0.f, sAz = 0.f, sBz = 0.f;
  if (lane < F) {
#pragma unroll 4
    for (int j = 0; j < 16; ++j) sA += csA[b0 + (size_t)j * F + lane];
#pragma unroll 4
    for (int j = 0; j < 16; ++j) sB += csB[b0 + (size_t)j * F + lane];
  }
  if (lane == 0) {
    for (int j = 0; j < 16; ++j) { sAz += csAz[hd * NC + g * 16 + j]; sBz += csBz[hd * NC + g * 16 + j]; }
  }
  if (lane < F) part[g][lane] = sA;
  if (lane == 0) partz[g] = sAz;
  __syncthreads();
  float baseA = 0.f, baseAz = 0.f;
  if (lane < F) for (int g2 = 0; g2 < g; ++g2) baseA += part[g2][lane];
  if (lane == 0) for (int g2 = 0; g2 < g; ++g2) baseAz += partz[g2];
  __syncthreads();
  if (lane < F) part[g][lane] = sB;
  if (lane == 0) partz[g] = sBz;
  __syncthreads();
  float baseB = 0.f, baseBz = 0.f;
  if (lane < F) for (int g2 = g + 1; g2 < 16; ++g2) baseB += part[g2][lane];
  if (lane == 0) for (int g2 = g + 1; g2 < 16; ++g2) baseBz += partz[g2];
  if (lane < F) {
    float run = baseA;
    for (int j = 0; j < 16; ++j) {
      size_t o = b0 + (size_t)j * F + lane;
      float tmp = csA[o]; csA[o] = run; run += tmp;
    }
    run = baseB;
    for (int j = 15; j >= 0; --j) {
      size_t o = b0 + (size_t)j * F + lane;
      float tmp = csB[o]; csB[o] = run; run += tmp;
    }
  }
  if (lane == 0) {
    float run = baseAz;
    for (int j = 0; j < 16; ++j) {
      int o = hd * NC + g * 16 + j;
      float tmp = csAz[o]; csAz[o] = run; run += tmp;
    }
    run = baseBz;
    for (int j = 15; j >= 0; --j) {
      int o = hd * NC + g * 16 + j;
      float tmp = csBz[o]; csBz[o] = run; run += tmp;
    }
  }
}

// ---------------------------------------------------------------------------
// K6: layer-1 combine WITHOUT P/Q tables: chunk bases (csA=prefix-before,
// csB=suffix-after) + in-chunk rebuild of the <=16 boundary terms from
// h/ts/perm. Binary search in LDS-staged ts. 4 rows/block (one per wave).
// ---------------------------------------------------------------------------
__global__ __launch_bounds__(256) void k_combine1(const float* __restrict__ s_src,
                                                  const float* __restrict__ ts,
                                                  const int* __restrict__ perm,
                                                  const float* __restrict__ h,
                                                  const float* __restrict__ csA,
                                                  const float* __restrict__ csB,
                                                  const float* __restrict__ csAz,
                                                  const float* __restrict__ csBz,
                                                  unsigned short* __restrict__ xcb) {
  int hd = blockIdx.x >> 10;          // 1024 blocks per head
  int i0 = (blockIdx.x & 1023) * 4;
  __shared__ float tsl[N];
  const float* tsh = ts + (size_t)hd * N;
  {
    int i4 = threadIdx.x * 4;
#pragma unroll
    for (int rep = 0; rep < 4; ++rep) {
      float4 v = *(const float4*)(tsh + i4 + rep * 1024);
      *(float4*)(tsl + i4 + rep * 1024) = v;
    }
  }
  __syncthreads();
  int wv = threadIdx.x >> 6, lane = threadIdx.x & 63;
  int i = i0 + wv;
  float s = s_src[(size_t)hd * N + i];
  float key = -s;
  int lo = 0, hi = N;
  while (lo < hi) {
    int mid = (lo + hi) >> 1;
    if (tsl[mid] <= key) lo = mid + 1; else hi = mid;
  }
  int k = lo;
  int c = (k >= N) ? (NC - 1) : (k >> 4);
  int c0 = c * 16;
  float tm = tsl[N - 1];
  float v = s + tm;
  float m = fmaxf(v, ALPHA * v);
  float wA = expf(ALPHA * v - m);
  float wB = expf(v - m);
  size_t cb = (size_t)hd * NC + c;
  float numA = csA[cb * NHID + lane];
  float numB = csB[cb * NHID + lane];
  float zA = csAz[cb], zB = csBz[cb];
  float tv16 = tsl[c0 + (lane & 15)];
  int   pv16 = perm[(size_t)hd * N + c0 + (lane & 15)];
#pragma unroll
  for (int r = 0; r < 16; ++r) {
    float tv = __shfl(tv16, r);
    int   p  = __shfl(pv16, r);
    float hv = h[((size_t)hd * N + p) * NHID + lane];
    bool isA = (c0 + r) < k;
    float e = expf((isA ? ALPHA : 1.f) * (tv - tm));
    if (isA) { numA += e * hv; zA += e; }
    else     { numB += e * hv; zB += e; }
  }
  float Z = wA * zA + wB * zB;
  float f = (wA * numA + wB * numB) / Z;
  float e2 = f > 0.f ? f : expf(f) - 1.f;
  xcb[(size_t)i * (NHEADS * NHID) + hd * NHID + lane] = f2bf(e2);
}

// ---------------------------------------------------------------------------
// K7: h2 = xc @ Wo via MFMA (M=4096, N=16, K=512) + fused layer-2 scores.
// ---------------------------------------------------------------------------
__global__ __launch_bounds__(256) void k_gemm2(const unsigned short* __restrict__ xcb,
                                               const unsigned short* __restrict__ Wt2,
                                               const float* __restrict__ ao,
                                               float* __restrict__ h2,
                                               float* __restrict__ ssrc,
                                               float* __restrict__ sdst) {
  const int t = threadIdx.x;
  const int w = t >> 6, lane = t & 63;
  const int lr = lane & 15, kg = lane >> 4;
  const int i0 = blockIdx.x * 64 + w * 16;
  f32x4 acc = (f32x4){0.f, 0.f, 0.f, 0.f};
  const unsigned short* arow = xcb + (size_t)(i0 + lr) * NFEAT;
  const unsigned short* brow = Wt2 + (size_t)lr * NFEAT;
#pragma unroll
  for (int k0 = 0; k0 < NFEAT; k0 += 32) {
    bf16x8 af = __builtin_bit_cast(bf16x8, *(const uint4*)(arow + k0 + kg * 8));
    bf16x8 bf = __builtin_bit_cast(bf16x8, *(const uint4*)(brow + k0 + kg * 8));
    acc = __builtin_amdgcn_mfma_f32_16x16x32_bf16(af, bf, acc, 0, 0, 0);
  }
  float aS = ao[lr], aD = ao[16 + lr];
#pragma unroll
  for (int reg = 0; reg < 4; ++reg) {
    int row = i0 + kg * 4 + reg;
    h2[(size_t)row * NCLASS + lr] = acc[reg];
    float ps = acc[reg] * aS, pd = acc[reg] * aD;
#pragma unroll
    for (int m = 1; m < 16; m <<= 1) { ps += __shfl_xor(ps, m); pd += __shfl_xor(pd, m); }
    if (lr == 0) { ssrc[row] = ps; sdst[row] = pd; }
  }
}

// ---------------------------------------------------------------------------
// K8: layer-2 combine (chunk bases + in-chunk rebuild) + ELU + log_softmax.
// 16 rows per block, 16 lanes per row.
// ---------------------------------------------------------------------------
__global__ __launch_bounds__(256) void k_combine2(const float* __restrict__ s_src,
                                                  const float* __restrict__ ts,
                                                  const int* __restrict__ perm,
                                                  const float* __restrict__ h2,
                                                  const float* __restrict__ csA,
                                                  const float* __restrict__ csB,
                                                  const float* __restrict__ csAz,
                                                  const float* __restrict__ csBz,
                                                  float* __restrict__ out) {
  __shared__ float tsl[N];
  {
    int i4 = threadIdx.x * 4;
#pragma unroll
    for (int rep = 0; rep < 4; ++rep) {
      float4 v = *(const float4*)(ts + i4 + rep * 1024);
      *(float4*)(tsl + i4 + rep * 1024) = v;
    }
  }
  __syncthreads();
  int g = threadIdx.x >> 4, cl = threadIdx.x & 15;
  int i = blockIdx.x * 16 + g;
  float s = s_src[i];
  float key = -s;
  int lo = 0, hi = N;
  while (lo < hi) {
    int mid = (lo + hi) >> 1;
    if (tsl[mid] <= key) lo = mid + 1; else hi = mid;
  }
  int k = lo;
  int c = (k >= N) ? (NC - 1) : (k >> 4);
  int c0 = c * 16;
  float tm = tsl[N - 1];
  float v = s + tm;
  float m = fmaxf(v, ALPHA * v);
  float wA = expf(ALPHA * v - m);
  float wB = expf(v - m);
  float numA = csA[(size_t)c * NCLASS + cl];
  float numB = csB[(size_t)c * NCLASS + cl];
  float zA = csAz[c], zB = csBz[c];
  float tvg = tsl[c0 + cl];
  int   pvg = perm[c0 + cl];
#pragma unroll
  for (int r = 0; r < 16; ++r) {
    float tv = __shfl(tvg, r, 16);
    int   p  = __shfl(pvg, r, 16);
    float hv = h2[(size_t)p * NCLASS + cl];
    bool isA = (c0 + r) < k;
    float e = expf((isA ? ALPHA : 1.f) * (tv - tm));
    if (isA) { numA += e * hv; zA += e; }
    else     { numB += e * hv; zB += e; }
  }
  float Z = wA * zA + wB * zB;
  float f = (wA * numA + wB * numB) / Z;
  float o = f > 0.f ? f : expf(f) - 1.f;
  float mx = o;
#pragma unroll
  for (int mk = 1; mk < 16; mk <<= 1) mx = fmaxf(mx, __shfl_xor(mx, mk, 16));
  float ex = expf(o - mx);
  float sum = ex;
#pragma unroll
  for (int mk = 1; mk < 16; mk <<= 1) sum += __shfl_xor(sum, mk, 16);
  out[(size_t)i * NCLASS + cl] = o - mx - logf(sum);
}

// ---------------------------------------------------------------------------
extern "C" void kernel_launch(void* const* d_in, const int* in_sizes, int n_in,
                              void* d_out, int out_size, void* d_ws, size_t ws_size,
                              hipStream_t stream) {
  const float* x  = (const float*)d_in[0];
  const float* Wh = (const float*)d_in[1];
  const float* ah = (const float*)d_in[2];
  const float* Wo = (const float*)d_in[3];
  const float* ao = (const float*)d_in[4];
  float* out = (float*)d_out;

  char* base = (char*)d_ws;
  size_t off = 0;
  auto alloc_f = [&](size_t n) -> float* {
    float* p = (float*)(base + off);
    off = (off + n * sizeof(float) + 255) & ~(size_t)255;
    return p;
  };
  auto alloc_i = [&](size_t n) -> int* {
    int* p = (int*)(base + off);
    off = (off + n * sizeof(int) + 255) & ~(size_t)255;
    return p;
  };
  auto alloc_u16 = [&](size_t n) -> unsigned short* {
    unsigned short* p = (unsigned short*)(base + off);
    off = (off + n * sizeof(unsigned short) + 255) & ~(size_t)255;
    return p;
  };

  unsigned short* xbf = alloc_u16((size_t)N * NFEAT);
  unsigned short* Wt  = alloc_u16((size_t)NHEADS * NHID * NFEAT);
  unsigned short* Wt2 = alloc_u16((size_t)NCLASS * NFEAT);
  float* h1    = alloc_f((size_t)NHEADS * N * NHID);
  float* ssrc1 = alloc_f((size_t)NHEADS * N);
  float* sdst1 = alloc_f((size_t)NHEADS * N);
  float* ts1   = alloc_f((size_t)NHEADS * N);
  int*   perm1 = alloc_i((size_t)NHEADS * N);
  float* csA1  = alloc_f((size_t)NHEADS * NC * NHID);
  float* csB1  = alloc_f((size_t)NHEADS * NC * NHID);
  float* csAz1 = alloc_f(NHEADS * NC);
  float* csBz1 = alloc_f(NHEADS * NC);
  unsigned short* xcb = alloc_u16((size_t)N * NHEADS * NHID);
  float* h2    = alloc_f((size_t)N * NCLASS);
  float* ssrc2 = alloc_f(N);
  float* sdst2 = alloc_f(N);
  float* ts2   = alloc_f(N);
  int*   perm2 = alloc_i(N);
  float* csA2  = alloc_f((size_t)NC * NCLASS);
  float* csB2  = alloc_f((size_t)NC * NCLASS);
  float* csAz2 = alloc_f(NC);
  float* csBz2 = alloc_f(NC);

  if (off > ws_size) return;

  // ---- pack (x, Wh, Wo) ----
  hipLaunchKernelGGL(k_pack, dim3(2113), dim3(256), 0, stream, x, Wh, Wo, xbf, Wt, Wt2);

  // ---- Layer 1 (8 heads) ----
  hipLaunchKernelGGL(k_gemm_h, dim3(N / 128, NHEADS), dim3(256), 0, stream, xbf, Wt, ah, h1, ssrc1, sdst1);
  hipLaunchKernelGGL(k_rank, dim3(64, NHEADS), dim3(256), 0, stream, sdst1, ts1, perm1);
  hipLaunchKernelGGL(k_chunksum, dim3(NC / 4, NHEADS), dim3(256), 0, stream, ts1, perm1, h1, csA1, csB1, csAz1, csBz1, NHID);
  hipLaunchKernelGGL(k_chunkscan, dim3(NHEADS), dim3(1024), 0, stream, csA1, csB1, csAz1, csBz1, NHID);
  hipLaunchKernelGGL(k_combine1, dim3(NHEADS * N / 4), dim3(256), 0, stream, ssrc1, ts1, perm1, h1, csA1, csB1, csAz1, csBz1, xcb);

  // ---- Layer 2 ----
  hipLaunchKernelGGL(k_gemm2, dim3(N / 64), dim3(256), 0, stream, xcb, Wt2, ao, h2, ssrc2, sdst2);
  hipLaunchKernelGGL(k_rank, dim3(64, 1), dim3(256), 0, stream, sdst2, ts2, perm2);
  hipLaunchKernelGGL(k_chunksum, dim3(NC / 4, 1), dim3(256), 0, stream, ts2, perm2, h2, csA2, csB2, csAz2, csBz2, NCLASS);
  hipLaunchKernelGGL(k_chunkscan, dim3(1), dim3(1024), 0, stream, csA2, csB2, csAz2, csBz2, NCLASS);
  hipLaunchKernelGGL(k_combine2, dim3(N / 16), dim3(256), 0, stream, ssrc2, ts2, perm2, h2, csA2, csB2, csAz2, csBz2, out);
}